// Round 1
// baseline (1744.012 us; speedup 1.0000x reference)
//
#include <hip/hip_runtime.h>
#include <math.h>

#define N_NODES 4096
#define T_NODES 1024
#define C_NODES 3072
#define F_IN    128
#define H_DIM   512
#define HEADS   16
#define D_HEAD  32
#define E_T     65536
#define E_C     98304
#define SCALE_QK 0.17677669529663687f   // 32^-0.5

// ---------------- P1/P2 projected embedding tables ----------------
// P1[i][h] = (edge_emb[i]/max(||.||,1)) . w_enc[:,h]   (16x16)
// P2[j][h] = (dist_emb[j]/max(||.||,1)) . w_dist[:,h]  (8x16)
__global__ void proj_tables_kernel(const float* __restrict__ emb,
                                   const float* __restrict__ dist_emb,
                                   const float* __restrict__ w_enc,
                                   const float* __restrict__ w_dist,
                                   float* __restrict__ P1,
                                   float* __restrict__ P2)
{
    __shared__ float inv1[16], inv2[8];
    int t = threadIdx.x;
    if (t < 16) {
        float s = 0.f;
        for (int f = 0; f < H_DIM; ++f) { float v = emb[t*H_DIM+f]; s += v*v; }
        inv1[t] = 1.0f / fmaxf(sqrtf(s), 1.0f);
    } else if (t < 24) {
        int j = t - 16;
        float s = 0.f;
        for (int f = 0; f < H_DIM; ++f) { float v = dist_emb[j*H_DIM+f]; s += v*v; }
        inv2[j] = 1.0f / fmaxf(sqrtf(s), 1.0f);
    }
    __syncthreads();
    {   // all 256 threads: one (i,h) each, 16*16 = 256
        int i = t >> 4, h = t & 15;
        float acc = 0.f;
        for (int f = 0; f < H_DIM; ++f) acc += emb[i*H_DIM+f] * w_enc[f*HEADS+h];
        P1[i*HEADS+h] = acc * inv1[i];
    }
    if (t < 128) { // 8*16 = 128
        int j = t >> 4, h = t & 15;
        float acc = 0.f;
        for (int f = 0; f < H_DIM; ++f) acc += dist_emb[j*H_DIM+f] * w_dist[f*HEADS+h];
        P2[j*HEADS+h] = acc * inv2[j];
    }
}

// ---------------- per-edge bias gather ----------------
__global__ void edge_bias_kernel(const int* __restrict__ rows, const int* __restrict__ cols,
                                 int row_off, int col_off, int E,
                                 const int* __restrict__ enc,    // N*N*2
                                 const int* __restrict__ dist,   // N*N
                                 const float* __restrict__ P1, const float* __restrict__ P2,
                                 const float* __restrict__ b_enc, const float* __restrict__ b_dist,
                                 float* __restrict__ bias)
{
    __shared__ float sP1[256], sP2[128], sb[16];
    int t = threadIdx.x;
    sP1[t] = P1[t];
    if (t < 128) sP2[t] = P2[t];
    if (t < 16)  sb[t]  = b_enc[t] + b_dist[t];
    __syncthreads();
    int gid = blockIdx.x * 256 + t;
    if (gid >= E * HEADS) return;
    int e = gid >> 4, h = gid & 15;
    long r = rows[e] + row_off;
    long c = cols[e] + col_off;
    long idx = r * N_NODES + c;
    int i1 = enc[idx*2], i2 = enc[idx*2+1];
    int j  = dist[idx];
    bias[gid] = 0.5f*(sP1[i1*HEADS+h] + sP1[i2*HEADS+h]) + sP2[j*HEADS+h] + sb[h];
}

// ---------------- CSR build ----------------
__global__ void hist_kernel(const int* __restrict__ rows, int E, int* __restrict__ counts) {
    int e = blockIdx.x * 256 + threadIdx.x;
    if (e < E) atomicAdd(&counts[rows[e]], 1);
}

__global__ void scan_kernel(const int* __restrict__ counts, int* __restrict__ offsets,
                            int* __restrict__ cursor, int n) {
    __shared__ int lds[1024];
    int t = threadIdx.x;
    int c = (n + 1023) / 1024;
    int base = t * c;
    int s = 0;
    for (int j = 0; j < c; ++j) { int i = base + j; if (i < n) s += counts[i]; }
    lds[t] = s;
    __syncthreads();
    for (int d = 1; d < 1024; d <<= 1) {
        int v = (t >= d) ? lds[t-d] : 0;
        __syncthreads();
        lds[t] += v;
        __syncthreads();
    }
    int run = lds[t] - s;  // exclusive
    for (int j = 0; j < c; ++j) {
        int i = base + j;
        if (i < n) { offsets[i] = run; cursor[i] = run; run += counts[i]; }
    }
    if (t == 1023) offsets[n] = lds[1023];
}

__global__ void scatter_kernel(const int* __restrict__ rows, int E,
                               int* __restrict__ cursor, int* __restrict__ perm) {
    int e = blockIdx.x * 256 + threadIdx.x;
    if (e < E) { int p = atomicAdd(&cursor[rows[e]], 1); perm[p] = e; }
}

// ---------------- LayerNorm (one wave per row) ----------------
__global__ void ln_kernel(const float* __restrict__ x, const float* __restrict__ g,
                          const float* __restrict__ b, float* __restrict__ y, int M) {
    int wave = threadIdx.x >> 6;      // 4 waves/block
    int lane = threadIdx.x & 63;
    int row = blockIdx.x * 4 + wave;
    if (row >= M) return;
    const float* xr = x + (long)row * H_DIM;
    float v[8];
    float s = 0.f, sq = 0.f;
    #pragma unroll
    for (int i = 0; i < 8; ++i) { v[i] = xr[lane + i*64]; s += v[i]; sq += v[i]*v[i]; }
    #pragma unroll
    for (int o = 1; o < 64; o <<= 1) { s += __shfl_xor(s, o, 64); sq += __shfl_xor(sq, o, 64); }
    float mean = s * (1.0f/512.0f);
    float var  = sq * (1.0f/512.0f) - mean*mean;
    float inv  = rsqrtf(var + 1e-5f);
    float* yr = y + (long)row * H_DIM;
    #pragma unroll
    for (int i = 0; i < 8; ++i) {
        int cidx = lane + i*64;
        yr[cidx] = (v[i] - mean) * inv * g[cidx] + b[cidx];
    }
}

// ---------------- f32 tiled GEMM: C = A(MxK) @ B(KxN) + bias ----------------
// MODE 0: store; MODE 1: store gelu(val); MODE 2: C += val (residual add)
template <int MODE>
__global__ __launch_bounds__(256) void gemm_kernel(const float* __restrict__ A,
                                                   const float* __restrict__ B,
                                                   const float* __restrict__ bias,
                                                   float* __restrict__ C,
                                                   int M, int Nn, int K)
{
    __shared__ float As[16][65];
    __shared__ float Bs[16][64];
    int tid = threadIdx.x;
    int tx = tid & 15, ty = tid >> 4;
    int m0 = blockIdx.y * 64, n0 = blockIdx.x * 64;
    float acc[4][4] = {};
    for (int k0 = 0; k0 < K; k0 += 16) {
        #pragma unroll
        for (int i = 0; i < 4; ++i) {
            int idx = tid + i*256;
            int m = idx >> 4, kk = idx & 15;
            As[kk][m] = A[(long)(m0+m)*K + k0 + kk];
        }
        #pragma unroll
        for (int i = 0; i < 4; ++i) {
            int idx = tid + i*256;
            int kk = idx >> 6, n = idx & 63;
            Bs[kk][n] = B[(long)(k0+kk)*Nn + n0 + n];
        }
        __syncthreads();
        #pragma unroll
        for (int kk = 0; kk < 16; ++kk) {
            float a[4], bb[4];
            #pragma unroll
            for (int i = 0; i < 4; ++i) a[i] = As[kk][ty*4+i];
            #pragma unroll
            for (int j = 0; j < 4; ++j) bb[j] = Bs[kk][tx*4+j];
            #pragma unroll
            for (int i = 0; i < 4; ++i)
                #pragma unroll
                for (int j = 0; j < 4; ++j)
                    acc[i][j] += a[i] * bb[j];
        }
        __syncthreads();
    }
    #pragma unroll
    for (int i = 0; i < 4; ++i) {
        int m = m0 + ty*4 + i;
        #pragma unroll
        for (int j = 0; j < 4; ++j) {
            int n = n0 + tx*4 + j;
            float val = acc[i][j] + bias[n];
            float* p = &C[(long)m*Nn + n];
            if (MODE == 0)      *p = val;
            else if (MODE == 1) *p = 0.5f * val * (1.0f + erff(val * 0.70710678118654752f));
            else                *p += val;
        }
    }
}

// ---------------- flash-style segment attention ----------------
// one 32-lane group per (row, head); lane = head dim
__global__ void attn_kernel(const float* __restrict__ q, const float* __restrict__ k,
                            const float* __restrict__ v, const float* __restrict__ bias,
                            const int* __restrict__ offsets, const int* __restrict__ perm,
                            const int* __restrict__ cols, float* __restrict__ o, int n_rows)
{
    int grp  = threadIdx.x >> 5;   // 8 groups / 256-thread block
    int lane = threadIdx.x & 31;
    int p = blockIdx.x * 8 + grp;
    if (p >= n_rows * HEADS) return;
    int r = p / HEADS, h = p % HEADS;
    float qv = q[(long)r*H_DIM + h*D_HEAD + lane];
    int beg = offsets[r], end = offsets[r+1];
    float m = -INFINITY, l = 0.f, acc = 0.f;
    for (int i = beg; i < end; ++i) {
        int e = perm[i];
        int c = cols[e];
        float kv = k[(long)c*H_DIM + h*D_HEAD + lane];
        float d = qv * kv;
        #pragma unroll
        for (int off = 16; off >= 1; off >>= 1) d += __shfl_xor(d, off, 32);
        float s = d * SCALE_QK + bias[e*HEADS + h];
        float m_new = fmaxf(m, s);
        float sc = __expf(m - m_new);      // 0 on first iter (m = -inf)
        float pw = __expf(s - m_new);
        l   = l * sc + pw;
        acc = acc * sc + pw * v[(long)c*H_DIM + h*D_HEAD + lane];
        m = m_new;
    }
    o[(long)r*H_DIM + h*D_HEAD + lane] = acc / (l + 1e-16f);
}

// ---------------- launcher ----------------
extern "C" void kernel_launch(void* const* d_in, const int* in_sizes, int n_in,
                              void* d_out, int out_size, void* d_ws, size_t ws_size,
                              hipStream_t stream)
{
    const float* node_feats = (const float*)d_in[0];
    const float* edge_emb   = (const float*)d_in[1];
    const float* dist_emb   = (const float*)d_in[2];
    const float* w_node     = (const float*)d_in[3];
    const float* b_node     = (const float*)d_in[4];
    const float* w_enc      = (const float*)d_in[5];
    const float* b_enc      = (const float*)d_in[6];
    const float* w_dist     = (const float*)d_in[7];
    const float* b_dist     = (const float*)d_in[8];
    const float* ln1_g      = (const float*)d_in[9];
    const float* ln1_b      = (const float*)d_in[10];
    const float* attn1_w    = (const float*)d_in[11];
    const float* attn1_b    = (const float*)d_in[12];
    const float* attn2_w    = (const float*)d_in[13];
    const float* attn2_b    = (const float*)d_in[14];
    const float* ln2_g      = (const float*)d_in[15];
    const float* ln2_b      = (const float*)d_in[16];
    const float* ffn_w1     = (const float*)d_in[17];
    const float* ffn_b1     = (const float*)d_in[18];
    const float* ffn_w2     = (const float*)d_in[19];
    const float* ffn_b2     = (const float*)d_in[20];
    const int* enc          = (const int*)d_in[21];
    const int* dist         = (const int*)d_in[22];
    const int* t_row        = (const int*)d_in[23];
    const int* t_col        = (const int*)d_in[24];
    const int* c_row        = (const int*)d_in[25];
    const int* c_col        = (const int*)d_in[26];

    float* x = (float*)d_out;   // 4096x512, fully overwritten by first GEMM

    char* w = (char*)d_ws;
    auto alloc_f = [&](size_t n) { float* p = (float*)w; w += n * sizeof(float); return p; };
    auto alloc_i = [&](size_t n) { int*   p = (int*)w;   w += n * sizeof(int);   return p; };
    float* y      = alloc_f((size_t)N_NODES * H_DIM);
    float* qb     = alloc_f((size_t)C_NODES * H_DIM);
    float* kb     = alloc_f((size_t)C_NODES * H_DIM);
    float* vb     = alloc_f((size_t)C_NODES * H_DIM);
    float* ob     = alloc_f((size_t)C_NODES * H_DIM);
    float* h1     = alloc_f((size_t)N_NODES * H_DIM);
    float* bias_t = alloc_f((size_t)E_T * HEADS);
    float* bias_c = alloc_f((size_t)E_C * HEADS);
    float* P1     = alloc_f(256);
    float* P2     = alloc_f(128);
    int* cnt_t  = alloc_i(T_NODES);
    int* off_t  = alloc_i(T_NODES + 1);
    int* cur_t  = alloc_i(T_NODES);
    int* perm_t = alloc_i(E_T);
    int* cnt_c  = alloc_i(C_NODES);
    int* off_c  = alloc_i(C_NODES + 1);
    int* cur_c  = alloc_i(C_NODES);
    int* perm_c = alloc_i(E_C);

    // ---- edge-bias tables + per-edge biases ----
    proj_tables_kernel<<<1, 256, 0, stream>>>(edge_emb, dist_emb, w_enc, w_dist, P1, P2);
    edge_bias_kernel<<<E_T*HEADS/256, 256, 0, stream>>>(t_row, t_col, 0, T_NODES, E_T,
                                                        enc, dist, P1, P2, b_enc, b_dist, bias_t);
    edge_bias_kernel<<<E_C*HEADS/256, 256, 0, stream>>>(c_row, c_col, T_NODES, 0, E_C,
                                                        enc, dist, P1, P2, b_enc, b_dist, bias_c);

    // ---- CSR builds (per side, once) ----
    hipMemsetAsync(cnt_t, 0, T_NODES * sizeof(int), stream);
    hipMemsetAsync(cnt_c, 0, C_NODES * sizeof(int), stream);
    hist_kernel<<<(E_T + 255)/256, 256, 0, stream>>>(t_row, E_T, cnt_t);
    hist_kernel<<<(E_C + 255)/256, 256, 0, stream>>>(c_row, E_C, cnt_c);
    scan_kernel<<<1, 1024, 0, stream>>>(cnt_t, off_t, cur_t, T_NODES);
    scan_kernel<<<1, 1024, 0, stream>>>(cnt_c, off_c, cur_c, C_NODES);
    scatter_kernel<<<(E_T + 255)/256, 256, 0, stream>>>(t_row, E_T, cur_t, perm_t);
    scatter_kernel<<<(E_C + 255)/256, 256, 0, stream>>>(c_row, E_C, cur_c, perm_c);

    // ---- x = node_feats @ w_node + b_node ----
    gemm_kernel<0><<<dim3(H_DIM/64, N_NODES/64), 256, 0, stream>>>(node_feats, w_node, b_node,
                                                                   x, N_NODES, H_DIM, F_IN);

    const size_t WSZ = (size_t)H_DIM * H_DIM;   // one 512x512 weight block
    for (int l = 0; l < 2; ++l) {
        // LN1
        ln_kernel<<<N_NODES/4, 256, 0, stream>>>(x, ln1_g + l*H_DIM, ln1_b + l*H_DIM, y, N_NODES);

        const float* W1 = attn1_w + (size_t)l*4*WSZ;
        const float* B1 = attn1_b + (size_t)l*4*H_DIM;
        const float* W2 = attn2_w + (size_t)l*4*WSZ;
        const float* B2 = attn2_b + (size_t)l*4*H_DIM;

        // ---- attn1: q from y[0:T), k/v from y[T:N) ----
        gemm_kernel<0><<<dim3(8, T_NODES/64), 256, 0, stream>>>(y,            W1 + 0*WSZ, B1 + 0*H_DIM, qb, T_NODES, H_DIM, H_DIM);
        gemm_kernel<0><<<dim3(8, C_NODES/64), 256, 0, stream>>>(y + (size_t)T_NODES*H_DIM, W1 + 1*WSZ, B1 + 1*H_DIM, kb, C_NODES, H_DIM, H_DIM);
        gemm_kernel<0><<<dim3(8, C_NODES/64), 256, 0, stream>>>(y + (size_t)T_NODES*H_DIM, W1 + 2*WSZ, B1 + 2*H_DIM, vb, C_NODES, H_DIM, H_DIM);
        attn_kernel<<<T_NODES*HEADS/8, 256, 0, stream>>>(qb, kb, vb, bias_t, off_t, perm_t, t_col, ob, T_NODES);
        // out1 adds into x rows [C, N)
        gemm_kernel<2><<<dim3(8, T_NODES/64), 256, 0, stream>>>(ob, W1 + 3*WSZ, B1 + 3*H_DIM,
                                                                x + (size_t)C_NODES*H_DIM, T_NODES, H_DIM, H_DIM);

        // ---- attn2: q from y[T:N), k/v from y[0:T) ----
        gemm_kernel<0><<<dim3(8, C_NODES/64), 256, 0, stream>>>(y + (size_t)T_NODES*H_DIM, W2 + 0*WSZ, B2 + 0*H_DIM, qb, C_NODES, H_DIM, H_DIM);
        gemm_kernel<0><<<dim3(8, T_NODES/64), 256, 0, stream>>>(y,            W2 + 1*WSZ, B2 + 1*H_DIM, kb, T_NODES, H_DIM, H_DIM);
        gemm_kernel<0><<<dim3(8, T_NODES/64), 256, 0, stream>>>(y,            W2 + 2*WSZ, B2 + 2*H_DIM, vb, T_NODES, H_DIM, H_DIM);
        attn_kernel<<<C_NODES*HEADS/8, 256, 0, stream>>>(qb, kb, vb, bias_c, off_c, perm_c, c_col, ob, C_NODES);
        // out2 adds into x rows [0, C)
        gemm_kernel<2><<<dim3(8, C_NODES/64), 256, 0, stream>>>(ob, W2 + 3*WSZ, B2 + 3*H_DIM,
                                                                x, C_NODES, H_DIM, H_DIM);

        // ---- FFN ----
        ln_kernel<<<N_NODES/4, 256, 0, stream>>>(x, ln2_g + l*H_DIM, ln2_b + l*H_DIM, y, N_NODES);
        gemm_kernel<1><<<dim3(8, N_NODES/64), 256, 0, stream>>>(y,  ffn_w1 + (size_t)l*WSZ, ffn_b1 + l*H_DIM, h1, N_NODES, H_DIM, H_DIM);
        gemm_kernel<2><<<dim3(8, N_NODES/64), 256, 0, stream>>>(h1, ffn_w2 + (size_t)l*WSZ, ffn_b2 + l*H_DIM, x,  N_NODES, H_DIM, H_DIM);
    }
}

// Round 2
// 580.028 us; speedup vs baseline: 3.0068x; 3.0068x over previous
//
#include <hip/hip_runtime.h>
#include <math.h>

#define N_NODES 4096
#define T_NODES 1024
#define C_NODES 3072
#define F_IN    128
#define H_DIM   512
#define HEADS   16
#define D_HEAD  32
#define E_T     65536
#define E_C     98304
#define SCALE_QK 0.17677669529663687f   // 32^-0.5

typedef __attribute__((ext_vector_type(8))) short short8;
typedef __attribute__((ext_vector_type(4))) float f32x4;

__device__ inline unsigned short f2bf(float f) {
    unsigned u = __float_as_uint(f);
    unsigned r = (u + 0x7fffu + ((u >> 16) & 1u)) >> 16;
    return (unsigned short)r;
}

__device__ inline void gload16(const void* g, void* l) {
    __builtin_amdgcn_global_load_lds(
        (const __attribute__((address_space(1))) unsigned int*)g,
        (__attribute__((address_space(3))) unsigned int*)l, 16, 0, 0);
}

// ---------------- transpose+convert f32 [R][C] -> bf16 [C][R] ----------------
struct TD { const float* src[20]; unsigned short* dst[20]; };

__global__ void tpose512_kernel(TD d) {
    int s = blockIdx.z;
    const float* src = d.src[s];
    unsigned short* dst = d.dst[s];
    __shared__ float tile[32][33];
    int r0 = blockIdx.y * 32, c0 = blockIdx.x * 32;
    int tr = threadIdx.x >> 5, tc = threadIdx.x & 31;
    #pragma unroll
    for (int p = 0; p < 4; ++p) tile[tr + 8*p][tc] = src[(size_t)(r0 + tr + 8*p)*512 + c0 + tc];
    __syncthreads();
    #pragma unroll
    for (int p = 0; p < 4; ++p) dst[(size_t)(c0 + tr + 8*p)*512 + r0 + tc] = f2bf(tile[tc][tr + 8*p]);
}

__global__ void tposeRC_kernel(const float* __restrict__ src, unsigned short* __restrict__ dst,
                               int R, int C) {
    __shared__ float tile[32][33];
    int r0 = blockIdx.y * 32, c0 = blockIdx.x * 32;
    int tr = threadIdx.x >> 5, tc = threadIdx.x & 31;
    #pragma unroll
    for (int p = 0; p < 4; ++p) tile[tr + 8*p][tc] = src[(size_t)(r0 + tr + 8*p)*C + c0 + tc];
    __syncthreads();
    #pragma unroll
    for (int p = 0; p < 4; ++p) dst[(size_t)(c0 + tr + 8*p)*R + r0 + tc] = f2bf(tile[tc][tr + 8*p]);
}

__global__ void cvt_bf16_kernel(const float* __restrict__ src, unsigned short* __restrict__ dst, int n4) {
    int i = blockIdx.x * 256 + threadIdx.x;
    if (i >= n4) return;
    float4 v = ((const float4*)src)[i];
    dst[i*4+0] = f2bf(v.x); dst[i*4+1] = f2bf(v.y);
    dst[i*4+2] = f2bf(v.z); dst[i*4+3] = f2bf(v.w);
}

// ---------------- P1/P2 projected embedding tables ----------------
__global__ void proj_tables_kernel(const float* __restrict__ emb,
                                   const float* __restrict__ dist_emb,
                                   const float* __restrict__ w_enc,
                                   const float* __restrict__ w_dist,
                                   float* __restrict__ P1, float* __restrict__ P2)
{
    __shared__ float inv1[16], inv2[8];
    int t = threadIdx.x;
    if (t < 16) {
        float s = 0.f;
        for (int f = 0; f < H_DIM; ++f) { float v = emb[t*H_DIM+f]; s += v*v; }
        inv1[t] = 1.0f / fmaxf(sqrtf(s), 1.0f);
    } else if (t < 24) {
        int j = t - 16;
        float s = 0.f;
        for (int f = 0; f < H_DIM; ++f) { float v = dist_emb[j*H_DIM+f]; s += v*v; }
        inv2[j] = 1.0f / fmaxf(sqrtf(s), 1.0f);
    }
    __syncthreads();
    {
        int i = t >> 4, h = t & 15;
        float acc = 0.f;
        for (int f = 0; f < H_DIM; ++f) acc += emb[i*H_DIM+f] * w_enc[f*HEADS+h];
        P1[i*HEADS+h] = acc * inv1[i];
    }
    if (t < 128) {
        int j = t >> 4, h = t & 15;
        float acc = 0.f;
        for (int f = 0; f < H_DIM; ++f) acc += dist_emb[j*H_DIM+f] * w_dist[f*HEADS+h];
        P2[j*HEADS+h] = acc * inv2[j];
    }
}

// ---------------- bias concat ----------------
__global__ void bcat_kernel(const float* __restrict__ a1b, const float* __restrict__ a2b,
                            float* __restrict__ bct, float* __restrict__ bcc) {
    int t = threadIdx.x;
    for (int l = 0; l < 2; ++l)
        for (int i = t; i < 512; i += 256) {
            bct[l*1536 + i]        = a1b[(l*4+0)*512 + i];
            bct[l*1536 + 512 + i]  = a2b[(l*4+1)*512 + i];
            bct[l*1536 + 1024 + i] = a2b[(l*4+2)*512 + i];
            bcc[l*1536 + i]        = a1b[(l*4+1)*512 + i];
            bcc[l*1536 + 512 + i]  = a1b[(l*4+2)*512 + i];
            bcc[l*1536 + 1024 + i] = a2b[(l*4+0)*512 + i];
        }
}

// ---------------- CSR build ----------------
__global__ void hist_kernel(const int* __restrict__ rows, int E, int* __restrict__ counts) {
    int e = blockIdx.x * 256 + threadIdx.x;
    if (e < E) atomicAdd(&counts[rows[e]], 1);
}

__global__ void scan_kernel(const int* __restrict__ counts, int* __restrict__ offsets,
                            int* __restrict__ cursor, int n) {
    __shared__ int lds[1024];
    int t = threadIdx.x;
    int c = (n + 1023) / 1024;
    int base = t * c;
    int s = 0;
    for (int j = 0; j < c; ++j) { int i = base + j; if (i < n) s += counts[i]; }
    lds[t] = s;
    __syncthreads();
    for (int d = 1; d < 1024; d <<= 1) {
        int v = (t >= d) ? lds[t-d] : 0;
        __syncthreads();
        lds[t] += v;
        __syncthreads();
    }
    int run = lds[t] - s;
    for (int j = 0; j < c; ++j) {
        int i = base + j;
        if (i < n) { offsets[i] = run; cursor[i] = run; run += counts[i]; }
    }
    if (t == 1023) offsets[n] = lds[1023];
}

__global__ void scatter_kernel(const int* __restrict__ rows, int E,
                               int* __restrict__ cursor, int* __restrict__ perm) {
    int e = blockIdx.x * 256 + threadIdx.x;
    if (e < E) { int p = atomicAdd(&cursor[rows[e]], 1); perm[p] = e; }
}

// ---------------- per-CSR-position bias (permuted, [head][pos] planes) ----------------
__global__ void bias_perm_kernel(const int* __restrict__ rows, const int* __restrict__ cols,
                                 const int* __restrict__ perm, int E, int roff, int coff,
                                 const int* __restrict__ enc, const int* __restrict__ dist,
                                 const float* __restrict__ P1, const float* __restrict__ P2,
                                 const float* __restrict__ b_enc, const float* __restrict__ b_dist,
                                 float* __restrict__ biasp, int* __restrict__ colp)
{
    __shared__ float sP1[256], sP2[128], sb[16];
    int t = threadIdx.x;
    sP1[t] = P1[t];
    if (t < 128) sP2[t] = P2[t];
    if (t < 16)  sb[t]  = b_enc[t] + b_dist[t];
    __syncthreads();
    int i = blockIdx.x * 256 + t;
    if (i >= E) return;
    int e = perm[i];
    long r = rows[e] + roff;
    long c = cols[e];
    long idx = r * N_NODES + c + coff;
    int i1 = enc[idx*2], i2 = enc[idx*2+1], j = dist[idx];
    colp[i] = (int)c;
    #pragma unroll
    for (int h = 0; h < 16; ++h)
        biasp[(size_t)h*E + i] = 0.5f*(sP1[i1*16+h] + sP1[i2*16+h]) + sP2[j*16+h] + sb[h];
}

// ---------------- LayerNorm: f32 in, bf16 out ----------------
__global__ void ln_kernel(const float* __restrict__ x, const float* __restrict__ g,
                          const float* __restrict__ b, unsigned short* __restrict__ y, int M) {
    int wave = threadIdx.x >> 6;
    int lane = threadIdx.x & 63;
    int row = blockIdx.x * 4 + wave;
    if (row >= M) return;
    const float* xr = x + (size_t)row * H_DIM;
    float v[8];
    float s = 0.f, sq = 0.f;
    #pragma unroll
    for (int i = 0; i < 8; ++i) { v[i] = xr[lane + i*64]; s += v[i]; sq += v[i]*v[i]; }
    #pragma unroll
    for (int o = 1; o < 64; o <<= 1) { s += __shfl_xor(s, o, 64); sq += __shfl_xor(sq, o, 64); }
    float mean = s * (1.0f/512.0f);
    float var  = sq * (1.0f/512.0f) - mean*mean;
    float inv  = rsqrtf(var + 1e-5f);
    unsigned short* yr = y + (size_t)row * H_DIM;
    #pragma unroll
    for (int i = 0; i < 8; ++i) {
        int cidx = lane + i*64;
        yr[cidx] = f2bf((v[i] - mean) * inv * g[cidx] + b[cidx]);
    }
}

// ---------------- bf16 MFMA GEMM: C(MxN) = A(MxK,bf16) @ BT(NxK,bf16)^T + bias ----------------
// MODE 0: store f32; MODE 1: store bf16 gelu(val); MODE 2: f32 C += val
// grid: (N/64, M/128), block 256 (4 waves, wave tile 64x32)
template <int MODE>
__global__ __launch_bounds__(256) void gemm_bf16(const unsigned short* __restrict__ A, int lda,
                                                 const unsigned short* __restrict__ BT, int ldb,
                                                 const float* __restrict__ bias,
                                                 void* __restrict__ Cout, int ldc, int K)
{
    __shared__ unsigned short As[2][128*32];   // [row][k], 8KB each
    __shared__ unsigned short Bs[2][64*32];    // [col][k], 4KB each
    int tid  = threadIdx.x;
    int wid  = tid >> 6, lane = tid & 63;
    int wm   = wid >> 1, wn = wid & 1;
    int m0   = blockIdx.y * 128, n0 = blockIdx.x * 64;

    // staging addresses (global side is per-lane; LDS side wave-uniform + lane*16)
    int srow  = lane >> 2;           // 0..15
    int sslot = lane & 3;            // 16B slot along K
    const unsigned short* Ag0 = A  + (size_t)(m0 + wid*32 + srow)*lda + sslot*8;
    const unsigned short* Ag1 = Ag0 + (size_t)16*lda;
    const unsigned short* Bg0 = BT + (size_t)(n0 + wid*16 + srow)*ldb + sslot*8;

    f32x4 acc[4][2] = {};
    int NT = K >> 5;

    auto stage = [&](int b, int kt) {
        const unsigned short* a0 = Ag0 + kt*32;
        const unsigned short* a1 = Ag1 + kt*32;
        const unsigned short* bb = Bg0 + kt*32;
        char* abase = (char*)&As[b][0] + wid*2048;
        char* bbase = (char*)&Bs[b][0] + wid*1024;
        gload16(a0, abase);
        gload16(a1, abase + 1024);
        gload16(bb, bbase);
    };

    stage(0, 0);
    __syncthreads();
    int cur = 0;
    int arowf = wm*64 + (lane & 15);
    int kslot = (lane >> 4) * 8;
    for (int kt = 0; kt < NT; ++kt) {
        if (kt + 1 < NT) stage(cur ^ 1, kt + 1);
        const unsigned short* as = &As[cur][0];
        const unsigned short* bs = &Bs[cur][0];
        short8 af[4], bf[2];
        #pragma unroll
        for (int fm = 0; fm < 4; ++fm)
            af[fm] = *(const short8*)&as[(arowf + fm*16)*32 + kslot];
        #pragma unroll
        for (int fn = 0; fn < 2; ++fn)
            bf[fn] = *(const short8*)&bs[(wn*32 + fn*16 + (lane & 15))*32 + kslot];
        #pragma unroll
        for (int fm = 0; fm < 4; ++fm)
            #pragma unroll
            for (int fn = 0; fn < 2; ++fn)
                acc[fm][fn] = __builtin_amdgcn_mfma_f32_16x16x32_bf16(af[fm], bf[fn], acc[fm][fn], 0, 0, 0);
        __syncthreads();
        cur ^= 1;
    }

    int crow = m0 + wm*64 + (lane >> 4)*4;
    int ccol = n0 + wn*32 + (lane & 15);
    #pragma unroll
    for (int fn = 0; fn < 2; ++fn) {
        float bv = bias[ccol + fn*16];
        #pragma unroll
        for (int fm = 0; fm < 4; ++fm) {
            #pragma unroll
            for (int j = 0; j < 4; ++j) {
                float val = acc[fm][fn][j] + bv;
                size_t off = (size_t)(crow + fm*16 + j)*ldc + ccol + fn*16;
                if (MODE == 0) {
                    ((float*)Cout)[off] = val;
                } else if (MODE == 1) {
                    float g = 0.5f * val * (1.0f + erff(val * 0.70710678118654752f));
                    ((unsigned short*)Cout)[off] = f2bf(g);
                } else {
                    ((float*)Cout)[off] += val;
                }
            }
        }
    }
}

// ---------------- wave-parallel segment attention ----------------
// 32-lane group per (row, head); chunks of 32 edges, lane-per-edge dot,
// then broadcast loop with coalesced v loads. Output bf16.
__global__ __launch_bounds__(256) void attn_kernel(
    const float* __restrict__ q, int ldq,
    const float* __restrict__ k, int ldk,
    const float* __restrict__ v, int ldv,
    const float* __restrict__ biasp, int Ecount,
    const int* __restrict__ offs, const int* __restrict__ colp,
    unsigned short* __restrict__ o, int n_rows)
{
    int grp = threadIdx.x >> 5, lane = threadIdx.x & 31;
    int p = blockIdx.x * 8 + grp;
    if (p >= n_rows * HEADS) return;
    int r = p >> 4, h = p & 15;

    const float4* qp = (const float4*)(q + (size_t)r*ldq + h*32);
    float4 qf[8];
    #pragma unroll
    for (int i = 0; i < 8; ++i) qf[i] = qp[i];

    int beg = offs[r], end = offs[r+1];
    const float* bias_h = biasp + (size_t)h * Ecount;
    float m = -INFINITY, l = 0.f, acc = 0.f;

    for (int i0 = beg; i0 < end; i0 += 32) {
        int i = i0 + lane;
        bool ok = i < end;
        int c = ok ? colp[i] : 0;
        float s = -INFINITY;
        if (ok) {
            float bv = bias_h[i];
            const float4* kp = (const float4*)(k + (size_t)c*ldk + h*32);
            float d = 0.f;
            #pragma unroll
            for (int j = 0; j < 8; ++j) {
                float4 kk = kp[j];
                d += qf[j].x*kk.x + qf[j].y*kk.y + qf[j].z*kk.z + qf[j].w*kk.w;
            }
            s = d * SCALE_QK + bv;
        }
        float cm = s;
        #pragma unroll
        for (int off2 = 16; off2 >= 1; off2 >>= 1) cm = fmaxf(cm, __shfl_xor(cm, off2, 32));
        float m_new = fmaxf(m, cm);
        float sc = __expf(m - m_new);         // 0 on first chunk
        float pw = __expf(s - m_new);         // 0 for invalid lanes
        float ps = pw;
        #pragma unroll
        for (int off2 = 16; off2 >= 1; off2 >>= 1) ps += __shfl_xor(ps, off2, 32);
        l = l * sc + ps;
        acc *= sc;
        int nv = min(32, end - i0);
        for (int e2 = 0; e2 < nv; ++e2) {
            float pwb = __shfl(pw, e2, 32);
            int   cb  = __shfl(c,  e2, 32);
            acc += pwb * v[(size_t)cb*ldv + h*32 + lane];
        }
        m = m_new;
    }
    o[(size_t)r*H_DIM + h*32 + lane] = f2bf(acc / (l + 1e-16f));
}

// ---------------- launcher ----------------
extern "C" void kernel_launch(void* const* d_in, const int* in_sizes, int n_in,
                              void* d_out, int out_size, void* d_ws, size_t ws_size,
                              hipStream_t stream)
{
    const float* node_feats = (const float*)d_in[0];
    const float* edge_emb   = (const float*)d_in[1];
    const float* dist_emb   = (const float*)d_in[2];
    const float* w_node     = (const float*)d_in[3];
    const float* b_node     = (const float*)d_in[4];
    const float* w_enc      = (const float*)d_in[5];
    const float* b_enc      = (const float*)d_in[6];
    const float* w_dist     = (const float*)d_in[7];
    const float* b_dist     = (const float*)d_in[8];
    const float* ln1_g      = (const float*)d_in[9];
    const float* ln1_b      = (const float*)d_in[10];
    const float* attn1_w    = (const float*)d_in[11];
    const float* attn1_b    = (const float*)d_in[12];
    const float* attn2_w    = (const float*)d_in[13];
    const float* attn2_b    = (const float*)d_in[14];
    const float* ln2_g      = (const float*)d_in[15];
    const float* ln2_b      = (const float*)d_in[16];
    const float* ffn_w1     = (const float*)d_in[17];
    const float* ffn_b1     = (const float*)d_in[18];
    const float* ffn_w2     = (const float*)d_in[19];
    const float* ffn_b2     = (const float*)d_in[20];
    const int* enc          = (const int*)d_in[21];
    const int* dist         = (const int*)d_in[22];
    const int* t_row        = (const int*)d_in[23];
    const int* t_col        = (const int*)d_in[24];
    const int* c_row        = (const int*)d_in[25];
    const int* c_col        = (const int*)d_in[26];

    float* x = (float*)d_out;   // 4096x512 f32

    char* w = (char*)d_ws;
    auto alloc = [&](size_t bytes) { char* p = w; w += (bytes + 255) & ~(size_t)255; return p; };

    unsigned short* yb   = (unsigned short*)alloc((size_t)N_NODES*H_DIM*2);
    float* qkv_c         = (float*)alloc((size_t)C_NODES*1536*4);
    char*  reg1          = alloc((size_t)T_NODES*1536*4);          // qkv_t | h1 | nf_bf
    float* qkv_t         = (float*)reg1;
    unsigned short* h1   = (unsigned short*)reg1;
    unsigned short* nfb  = (unsigned short*)reg1;
    unsigned short* ob_t = (unsigned short*)alloc((size_t)T_NODES*H_DIM*2);
    unsigned short* ob_c = (unsigned short*)alloc((size_t)C_NODES*H_DIM*2);
    float* biasp_t       = (float*)alloc((size_t)HEADS*E_T*4);
    float* biasp_c       = (float*)alloc((size_t)HEADS*E_C*4);
    int* colp_t          = (int*)alloc((size_t)E_T*4);
    int* colp_c          = (int*)alloc((size_t)E_C*4);
    int* cnt_t           = (int*)alloc(T_NODES*4);
    int* off_t           = (int*)alloc((T_NODES+1)*4);
    int* cur_t           = (int*)alloc(T_NODES*4);
    int* perm_t          = (int*)alloc((size_t)E_T*4);
    int* cnt_c           = (int*)alloc(C_NODES*4);
    int* off_c           = (int*)alloc((C_NODES+1)*4);
    int* cur_c           = (int*)alloc(C_NODES*4);
    int* perm_c          = (int*)alloc((size_t)E_C*4);
    float* P1            = (float*)alloc(256*4);
    float* P2            = (float*)alloc(128*4);
    unsigned short* wcat_t = (unsigned short*)alloc((size_t)2*1536*512*2);
    unsigned short* wcat_c = (unsigned short*)alloc((size_t)2*1536*512*2);
    unsigned short* wo1    = (unsigned short*)alloc((size_t)2*512*512*2);
    unsigned short* wo2    = (unsigned short*)alloc((size_t)2*512*512*2);
    unsigned short* wf1    = (unsigned short*)alloc((size_t)2*512*512*2);
    unsigned short* wf2    = (unsigned short*)alloc((size_t)2*512*512*2);
    unsigned short* wnT    = (unsigned short*)alloc((size_t)H_DIM*F_IN*2);
    float* bcat_t        = (float*)alloc(2*1536*4);
    float* bcat_c        = (float*)alloc(2*1536*4);

    const size_t SZ = 512*512;

    // ---- weight transposes (batched) ----
    TD td;
    for (int l = 0; l < 2; ++l) {
        int b = l*10;
        td.src[b+0] = attn1_w + (size_t)(l*4+0)*SZ;  td.dst[b+0] = wcat_t + (size_t)l*1536*512;
        td.src[b+1] = attn2_w + (size_t)(l*4+1)*SZ;  td.dst[b+1] = wcat_t + (size_t)l*1536*512 + SZ;
        td.src[b+2] = attn2_w + (size_t)(l*4+2)*SZ;  td.dst[b+2] = wcat_t + (size_t)l*1536*512 + 2*SZ;
        td.src[b+3] = attn1_w + (size_t)(l*4+1)*SZ;  td.dst[b+3] = wcat_c + (size_t)l*1536*512;
        td.src[b+4] = attn1_w + (size_t)(l*4+2)*SZ;  td.dst[b+4] = wcat_c + (size_t)l*1536*512 + SZ;
        td.src[b+5] = attn2_w + (size_t)(l*4+0)*SZ;  td.dst[b+5] = wcat_c + (size_t)l*1536*512 + 2*SZ;
        td.src[b+6] = attn1_w + (size_t)(l*4+3)*SZ;  td.dst[b+6] = wo1 + (size_t)l*SZ;
        td.src[b+7] = attn2_w + (size_t)(l*4+3)*SZ;  td.dst[b+7] = wo2 + (size_t)l*SZ;
        td.src[b+8] = ffn_w1  + (size_t)l*SZ;        td.dst[b+8] = wf1 + (size_t)l*SZ;
        td.src[b+9] = ffn_w2  + (size_t)l*SZ;        td.dst[b+9] = wf2 + (size_t)l*SZ;
    }
    tpose512_kernel<<<dim3(16,16,20), 256, 0, stream>>>(td);
    tposeRC_kernel<<<dim3(16,4), 256, 0, stream>>>(w_node, wnT, F_IN, H_DIM);
    cvt_bf16_kernel<<<(N_NODES*F_IN/4 + 255)/256, 256, 0, stream>>>(node_feats, nfb, N_NODES*F_IN/4);
    proj_tables_kernel<<<1, 256, 0, stream>>>(edge_emb, dist_emb, w_enc, w_dist, P1, P2);
    bcat_kernel<<<1, 256, 0, stream>>>(attn1_b, attn2_b, bcat_t, bcat_c);

    // ---- CSR builds ----
    hipMemsetAsync(cnt_t, 0, T_NODES*4, stream);
    hipMemsetAsync(cnt_c, 0, C_NODES*4, stream);
    hist_kernel<<<(E_T+255)/256, 256, 0, stream>>>(t_row, E_T, cnt_t);
    hist_kernel<<<(E_C+255)/256, 256, 0, stream>>>(c_row, E_C, cnt_c);
    scan_kernel<<<1, 1024, 0, stream>>>(cnt_t, off_t, cur_t, T_NODES);
    scan_kernel<<<1, 1024, 0, stream>>>(cnt_c, off_c, cur_c, C_NODES);
    scatter_kernel<<<(E_T+255)/256, 256, 0, stream>>>(t_row, E_T, cur_t, perm_t);
    scatter_kernel<<<(E_C+255)/256, 256, 0, stream>>>(c_row, E_C, cur_c, perm_c);

    // ---- permuted biases ----
    bias_perm_kernel<<<(E_T+255)/256, 256, 0, stream>>>(t_row, t_col, perm_t, E_T, 0, T_NODES,
                                                        enc, dist, P1, P2, b_enc, b_dist, biasp_t, colp_t);
    bias_perm_kernel<<<(E_C+255)/256, 256, 0, stream>>>(c_row, c_col, perm_c, E_C, T_NODES, 0,
                                                        enc, dist, P1, P2, b_enc, b_dist, biasp_c, colp_c);

    // ---- x = node_feats @ w_node + b_node  (K=128) ----
    gemm_bf16<0><<<dim3(H_DIM/64, N_NODES/128), 256, 0, stream>>>(nfb, F_IN, wnT, F_IN, b_node, x, H_DIM, F_IN);

    for (int l = 0; l < 2; ++l) {
        // LN1 -> yb (bf16)
        ln_kernel<<<N_NODES/4, 256, 0, stream>>>(x, ln1_g + l*H_DIM, ln1_b + l*H_DIM, yb, N_NODES);

        // fused QKV GEMMs:
        // qkv_t cols: [q1 | k2 | v2];  qkv_c cols: [k1 | v1 | q2]
        gemm_bf16<0><<<dim3(1536/64, T_NODES/128), 256, 0, stream>>>(
            yb, H_DIM, wcat_t + (size_t)l*1536*512, H_DIM, bcat_t + l*1536, qkv_t, 1536, H_DIM);
        gemm_bf16<0><<<dim3(1536/64, C_NODES/128), 256, 0, stream>>>(
            yb + (size_t)T_NODES*H_DIM, H_DIM, wcat_c + (size_t)l*1536*512, H_DIM, bcat_c + l*1536, qkv_c, 1536, H_DIM);

        // attn1: q=qkv_t[:,0:512], k=qkv_c[:,0:512], v=qkv_c[:,512:1024]
        attn_kernel<<<T_NODES*HEADS/8, 256, 0, stream>>>(qkv_t, 1536, qkv_c, 1536, qkv_c + 512, 1536,
                                                         biasp_t, E_T, off_t, colp_t, ob_t, T_NODES);
        // attn2: q=qkv_c[:,1024:1536], k=qkv_t[:,512:1024], v=qkv_t[:,1024:1536]
        attn_kernel<<<C_NODES*HEADS/8, 256, 0, stream>>>(qkv_c + 1024, 1536, qkv_t + 512, 1536, qkv_t + 1024, 1536,
                                                         biasp_c, E_C, off_c, colp_c, ob_c, C_NODES);

        // out1 -> x rows [C, N);  out2 -> x rows [0, C)
        gemm_bf16<2><<<dim3(H_DIM/64, T_NODES/128), 256, 0, stream>>>(
            ob_t, H_DIM, wo1 + (size_t)l*SZ, H_DIM, attn1_b + (size_t)(l*4+3)*H_DIM,
            x + (size_t)C_NODES*H_DIM, H_DIM, H_DIM);
        gemm_bf16<2><<<dim3(H_DIM/64, C_NODES/128), 256, 0, stream>>>(
            ob_c, H_DIM, wo2 + (size_t)l*SZ, H_DIM, attn2_b + (size_t)(l*4+3)*H_DIM,
            x, H_DIM, H_DIM);

        // FFN
        ln_kernel<<<N_NODES/4, 256, 0, stream>>>(x, ln2_g + l*H_DIM, ln2_b + l*H_DIM, yb, N_NODES);
        gemm_bf16<1><<<dim3(H_DIM/64, N_NODES/128), 256, 0, stream>>>(
            yb, H_DIM, wf1 + (size_t)l*SZ, H_DIM, ffn_b1 + l*H_DIM, h1, H_DIM, H_DIM);
        gemm_bf16<2><<<dim3(H_DIM/64, N_NODES/128), 256, 0, stream>>>(
            h1, H_DIM, wf2 + (size_t)l*SZ, H_DIM, ffn_b2 + l*H_DIM, x, H_DIM, H_DIM);
    }
}

// Round 3
// 361.222 us; speedup vs baseline: 4.8281x; 1.6057x over previous
//
#include <hip/hip_runtime.h>
#include <math.h>

#define N_NODES 4096
#define T_NODES 1024
#define C_NODES 3072
#define F_IN    128
#define H_DIM   512
#define HEADS   16
#define D_HEAD  32
#define E_T     65536
#define E_C     98304
#define SCALE_QK 0.17677669529663687f   // 32^-0.5

typedef __attribute__((ext_vector_type(8))) short short8;
typedef __attribute__((ext_vector_type(4))) float f32x4;

struct ushort4_t { unsigned short x, y, z, w; };

__device__ inline unsigned short f2bf(float f) {
    unsigned u = __float_as_uint(f);
    unsigned r = (u + 0x7fffu + ((u >> 16) & 1u)) >> 16;
    return (unsigned short)r;
}
__device__ inline float bf2f(unsigned short u) {
    return __uint_as_float(((unsigned)u) << 16);
}

__device__ inline void gload16(const void* g, void* l) {
    __builtin_amdgcn_global_load_lds(
        (const __attribute__((address_space(1))) unsigned int*)g,
        (__attribute__((address_space(3))) unsigned int*)l, 16, 0, 0);
}

// ================= fused preprocessing: transposes + node-feat convert =================
struct TD { const float* src[20]; unsigned short* dst[20]; };

__global__ void prep_kernel(TD d, const float* __restrict__ w_node, unsigned short* __restrict__ wnT,
                            const float* __restrict__ nf, unsigned short* __restrict__ nfb)
{
    int z = blockIdx.z;
    __shared__ float tile[32][33];
    int tr = threadIdx.x >> 5, tc = threadIdx.x & 31;
    if (z < 20) {
        const float* src = d.src[z];
        unsigned short* dst = d.dst[z];
        int r0 = blockIdx.y * 32, c0 = blockIdx.x * 32;
        #pragma unroll
        for (int p = 0; p < 4; ++p) tile[tr + 8*p][tc] = src[(size_t)(r0 + tr + 8*p)*512 + c0 + tc];
        __syncthreads();
        #pragma unroll
        for (int p = 0; p < 4; ++p) dst[(size_t)(c0 + tr + 8*p)*512 + r0 + tc] = f2bf(tile[tc][tr + 8*p]);
    } else if (z == 20) {
        if (blockIdx.y >= 4) return;   // w_node is 128x512
        int r0 = blockIdx.y * 32, c0 = blockIdx.x * 32;
        #pragma unroll
        for (int p = 0; p < 4; ++p) tile[tr + 8*p][tc] = w_node[(size_t)(r0 + tr + 8*p)*512 + c0 + tc];
        __syncthreads();
        #pragma unroll
        for (int p = 0; p < 4; ++p) wnT[(size_t)(c0 + tr + 8*p)*128 + r0 + tc] = f2bf(tile[tc][tr + 8*p]);
    } else {
        // node_feats f32 -> bf16, 4096*128 = 524288 elems = 131072 float4
        int gid = (blockIdx.y * 16 + blockIdx.x) * 256 + threadIdx.x;
        #pragma unroll
        for (int rep = 0; rep < 2; ++rep) {
            int i = gid + rep * 65536;
            float4 v = ((const float4*)nf)[i];
            ushort4_t o = { f2bf(v.x), f2bf(v.y), f2bf(v.z), f2bf(v.w) };
            ((ushort4_t*)nfb)[i] = o;
        }
    }
}

// ================= P1/P2 tables (wave-per-output) + bias concat =================
__global__ void proj_kernel(const float* __restrict__ emb, const float* __restrict__ dist_emb,
                            const float* __restrict__ w_enc, const float* __restrict__ w_dist,
                            const float* __restrict__ a1b, const float* __restrict__ a2b,
                            float* __restrict__ P1, float* __restrict__ P2,
                            float* __restrict__ bct, float* __restrict__ bcc)
{
    if (blockIdx.x == 96) {   // bias concat
        int t = threadIdx.x;
        for (int l = 0; l < 2; ++l)
            for (int i = t; i < 512; i += 256) {
                bct[l*1536 + i]        = a1b[(l*4+0)*512 + i];
                bct[l*1536 + 512 + i]  = a2b[(l*4+1)*512 + i];
                bct[l*1536 + 1024 + i] = a2b[(l*4+2)*512 + i];
                bcc[l*1536 + i]        = a1b[(l*4+1)*512 + i];
                bcc[l*1536 + 512 + i]  = a1b[(l*4+2)*512 + i];
                bcc[l*1536 + 1024 + i] = a2b[(l*4+0)*512 + i];
            }
        return;
    }
    int wid = threadIdx.x >> 6, lane = threadIdx.x & 63;
    int o = blockIdx.x * 4 + wid;   // 0..383
    const float* src; const float* wm; float* dst; int h;
    if (o < 256) { src = emb      + (size_t)(o >> 4) * 512; wm = w_enc;  h = o & 15;  dst = P1 + o; }
    else { int o2 = o - 256; src = dist_emb + (size_t)(o2 >> 4) * 512; wm = w_dist; h = o2 & 15; dst = P2 + o2; }
    float4 v0 = ((const float4*)src)[lane*2];
    float4 v1 = ((const float4*)src)[lane*2+1];
    float nrm = v0.x*v0.x + v0.y*v0.y + v0.z*v0.z + v0.w*v0.w
              + v1.x*v1.x + v1.y*v1.y + v1.z*v1.z + v1.w*v1.w;
    int f0 = lane * 8;
    float dt = v0.x*wm[(f0+0)*16+h] + v0.y*wm[(f0+1)*16+h] + v0.z*wm[(f0+2)*16+h] + v0.w*wm[(f0+3)*16+h]
             + v1.x*wm[(f0+4)*16+h] + v1.y*wm[(f0+5)*16+h] + v1.z*wm[(f0+6)*16+h] + v1.w*wm[(f0+7)*16+h];
    #pragma unroll
    for (int s = 1; s < 64; s <<= 1) { nrm += __shfl_xor(nrm, s, 64); dt += __shfl_xor(dt, s, 64); }
    if (lane == 0) *dst = dt / fmaxf(sqrtf(nrm), 1.0f);
}

// ================= CSR build (both sides fused) =================
__global__ void hist2_kernel(const int* __restrict__ t_row, const int* __restrict__ c_row,
                             int* __restrict__ cnt_t, int* __restrict__ cnt_c) {
    int i = blockIdx.x * 256 + threadIdx.x;
    if (i < E_T) atomicAdd(&cnt_t[t_row[i]], 1);
    else atomicAdd(&cnt_c[c_row[i - E_T]], 1);
}

__global__ void scan2_kernel(const int* __restrict__ cnt_t, int* __restrict__ off_t, int* __restrict__ cur_t,
                             const int* __restrict__ cnt_c, int* __restrict__ off_c, int* __restrict__ cur_c) {
    const int* counts; int* offsets; int* cursor; int n;
    if (blockIdx.x == 0) { counts = cnt_t; offsets = off_t; cursor = cur_t; n = T_NODES; }
    else                 { counts = cnt_c; offsets = off_c; cursor = cur_c; n = C_NODES; }
    __shared__ int lds[1024];
    int t = threadIdx.x;
    int c = (n + 1023) / 1024;
    int base = t * c;
    int s = 0;
    for (int j = 0; j < c; ++j) { int i = base + j; if (i < n) s += counts[i]; }
    lds[t] = s;
    __syncthreads();
    for (int d = 1; d < 1024; d <<= 1) {
        int v = (t >= d) ? lds[t-d] : 0;
        __syncthreads();
        lds[t] += v;
        __syncthreads();
    }
    int run = lds[t] - s;
    for (int j = 0; j < c; ++j) {
        int i = base + j;
        if (i < n) { offsets[i] = run; cursor[i] = run; run += counts[i]; }
    }
    if (t == 1023) offsets[n] = lds[1023];
}

__global__ void scatter2_kernel(const int* __restrict__ t_row, const int* __restrict__ c_row,
                                int* __restrict__ cur_t, int* __restrict__ cur_c,
                                int* __restrict__ perm_t, int* __restrict__ perm_c) {
    int i = blockIdx.x * 256 + threadIdx.x;
    if (i < E_T) { int p = atomicAdd(&cur_t[t_row[i]], 1); perm_t[p] = i; }
    else { int j = i - E_T; int p = atomicAdd(&cur_c[c_row[j]], 1); perm_c[p] = j; }
}

// ================= per-CSR-position bias, [head][pos] planes (both sides) =================
__global__ void bias2_kernel(const int* __restrict__ t_row, const int* __restrict__ t_col,
                             const int* __restrict__ c_row, const int* __restrict__ c_col,
                             const int* __restrict__ perm_t, const int* __restrict__ perm_c,
                             const int* __restrict__ enc, const int* __restrict__ dist,
                             const float* __restrict__ P1, const float* __restrict__ P2,
                             const float* __restrict__ b_enc, const float* __restrict__ b_dist,
                             float* __restrict__ biasp_t, float* __restrict__ biasp_c,
                             int* __restrict__ colp_t, int* __restrict__ colp_c)
{
    __shared__ float sP1[256], sP2[128], sb[16];
    int t = threadIdx.x;
    sP1[t] = P1[t];
    if (t < 128) sP2[t] = P2[t];
    if (t < 16)  sb[t]  = b_enc[t] + b_dist[t];
    __syncthreads();
    int gi = blockIdx.x * 256 + t;
    long r, c; int i, E; float* biasp; int* colp;
    if (gi < E_T) {
        i = gi; int e = perm_t[i];
        r = t_row[e]; c = t_col[e];
        long idx = r * N_NODES + c + T_NODES;
        int i1 = enc[idx*2], i2 = enc[idx*2+1], j = dist[idx];
        colp_t[i] = (int)c;
        #pragma unroll
        for (int h = 0; h < 16; ++h)
            biasp_t[(size_t)h*E_T + i] = 0.5f*(sP1[i1*16+h] + sP1[i2*16+h]) + sP2[j*16+h] + sb[h];
    } else {
        i = gi - E_T; int e = perm_c[i];
        r = c_row[e] + T_NODES; c = c_col[e];
        long idx = r * N_NODES + c;
        int i1 = enc[idx*2], i2 = enc[idx*2+1], j = dist[idx];
        colp_c[i] = (int)c;
        #pragma unroll
        for (int h = 0; h < 16; ++h)
            biasp_c[(size_t)h*E_C + i] = 0.5f*(sP1[i1*16+h] + sP1[i2*16+h]) + sP2[j*16+h] + sb[h];
    }
    (void)E; (void)biasp; (void)colp;
}

// ================= LayerNorm: f32 in, bf16 out (vectorized) =================
__global__ void ln_kernel(const float* __restrict__ x, const float* __restrict__ g,
                          const float* __restrict__ b, unsigned short* __restrict__ y, int M) {
    int wave = threadIdx.x >> 6;
    int lane = threadIdx.x & 63;
    int row = blockIdx.x * 4 + wave;
    if (row >= M) return;
    const float4* xr = (const float4*)(x + (size_t)row * H_DIM);
    float4 a = xr[lane*2], c4 = xr[lane*2+1];
    float s  = a.x + a.y + a.z + a.w + c4.x + c4.y + c4.z + c4.w;
    float sq = a.x*a.x + a.y*a.y + a.z*a.z + a.w*a.w + c4.x*c4.x + c4.y*c4.y + c4.z*c4.z + c4.w*c4.w;
    #pragma unroll
    for (int o = 1; o < 64; o <<= 1) { s += __shfl_xor(s, o, 64); sq += __shfl_xor(sq, o, 64); }
    float mean = s * (1.0f/512.0f);
    float var  = sq * (1.0f/512.0f) - mean*mean;
    float inv  = rsqrtf(var + 1e-5f);
    const float4* gp = (const float4*)g;
    const float4* bp = (const float4*)b;
    float4 g0 = gp[lane*2], g1 = gp[lane*2+1];
    float4 b0 = bp[lane*2], b1 = bp[lane*2+1];
    ushort4_t o0 = { f2bf((a.x-mean)*inv*g0.x + b0.x), f2bf((a.y-mean)*inv*g0.y + b0.y),
                     f2bf((a.z-mean)*inv*g0.z + b0.z), f2bf((a.w-mean)*inv*g0.w + b0.w) };
    ushort4_t o1 = { f2bf((c4.x-mean)*inv*g1.x + b1.x), f2bf((c4.y-mean)*inv*g1.y + b1.y),
                     f2bf((c4.z-mean)*inv*g1.z + b1.z), f2bf((c4.w-mean)*inv*g1.w + b1.w) };
    ushort4_t* yr = (ushort4_t*)(y + (size_t)row * H_DIM);
    yr[lane*2] = o0; yr[lane*2+1] = o1;
}

// ================= bf16 MFMA GEMM with per-block-row weight select =================
// C(MxN) = A(MxK,bf16) @ W^T + bias ; W = (m0 < mswitch ? Wa : Wb), same for bias
// MODE 0: store f32; MODE 1: store bf16 gelu; MODE 2: f32 +=; MODE 3: store bf16
template <int MODE>
__global__ __launch_bounds__(256) void gemm_bf16(
    const unsigned short* __restrict__ A, int lda,
    const unsigned short* __restrict__ Wa, const unsigned short* __restrict__ Wb, int ldb,
    const float* __restrict__ biasa, const float* __restrict__ biasb,
    void* __restrict__ Cout, int ldc, int K, int mswitch)
{
    __shared__ unsigned short As[2][128*32];
    __shared__ unsigned short Bs[2][64*32];
    int tid  = threadIdx.x;
    int wid  = tid >> 6, lane = tid & 63;
    int wm   = wid >> 1, wn = wid & 1;
    int m0   = blockIdx.y * 128, n0 = blockIdx.x * 64;
    const unsigned short* BT = (m0 >= mswitch) ? Wb : Wa;
    const float* bias        = (m0 >= mswitch) ? biasb : biasa;

    int srow  = lane >> 2;
    int sslot = lane & 3;
    const unsigned short* Ag0 = A  + (size_t)(m0 + wid*32 + srow)*lda + sslot*8;
    const unsigned short* Ag1 = Ag0 + (size_t)16*lda;
    const unsigned short* Bg0 = BT + (size_t)(n0 + wid*16 + srow)*ldb + sslot*8;

    f32x4 acc[4][2] = {};
    int NT = K >> 5;

    auto stage = [&](int bsel, int kt) {
        char* abase = (char*)&As[bsel][0] + wid*2048;
        char* bbase = (char*)&Bs[bsel][0] + wid*1024;
        gload16(Ag0 + kt*32, abase);
        gload16(Ag1 + kt*32, abase + 1024);
        gload16(Bg0 + kt*32, bbase);
    };

    stage(0, 0);
    __syncthreads();
    int cur = 0;
    int arowf = wm*64 + (lane & 15);
    int kslot = (lane >> 4) * 8;
    for (int kt = 0; kt < NT; ++kt) {
        if (kt + 1 < NT) stage(cur ^ 1, kt + 1);
        const unsigned short* as = &As[cur][0];
        const unsigned short* bs = &Bs[cur][0];
        short8 af[4], bf[2];
        #pragma unroll
        for (int fm = 0; fm < 4; ++fm)
            af[fm] = *(const short8*)&as[(arowf + fm*16)*32 + kslot];
        #pragma unroll
        for (int fn = 0; fn < 2; ++fn)
            bf[fn] = *(const short8*)&bs[(wn*32 + fn*16 + (lane & 15))*32 + kslot];
        #pragma unroll
        for (int fm = 0; fm < 4; ++fm)
            #pragma unroll
            for (int fn = 0; fn < 2; ++fn)
                acc[fm][fn] = __builtin_amdgcn_mfma_f32_16x16x32_bf16(af[fm], bf[fn], acc[fm][fn], 0, 0, 0);
        __syncthreads();
        cur ^= 1;
    }

    int crow = m0 + wm*64 + (lane >> 4)*4;
    int ccol = n0 + wn*32 + (lane & 15);
    #pragma unroll
    for (int fn = 0; fn < 2; ++fn) {
        float bv = bias[ccol + fn*16];
        #pragma unroll
        for (int fm = 0; fm < 4; ++fm) {
            #pragma unroll
            for (int j = 0; j < 4; ++j) {
                float val = acc[fm][fn][j] + bv;
                size_t off = (size_t)(crow + fm*16 + j)*ldc + ccol + fn*16;
                if (MODE == 0) {
                    ((float*)Cout)[off] = val;
                } else if (MODE == 1) {
                    float gl = 0.5f * val * (1.0f + erff(val * 0.70710678118654752f));
                    ((unsigned short*)Cout)[off] = f2bf(gl);
                } else if (MODE == 2) {
                    ((float*)Cout)[off] += val;
                } else {
                    ((unsigned short*)Cout)[off] = f2bf(val);
                }
            }
        }
    }
}

// ================= fused segment attention (both sides, bf16 operands) =================
// qkv layout [4096][1536] bf16:
//  rows 0..T    : [q1 | k2 | v2]
//  rows T..4096 : [k1 | v1 | q2]
// ob layout [4096][512] bf16: rows 0..C = attn2 out, rows C..N = attn1 out
__global__ __launch_bounds__(256) void attn_fused(
    const unsigned short* __restrict__ qkv,
    const float* __restrict__ biasp_t, const float* __restrict__ biasp_c,
    const int* __restrict__ off_t, const int* __restrict__ colp_t,
    const int* __restrict__ off_c, const int* __restrict__ colp_c,
    unsigned short* __restrict__ ob)
{
    int grp = threadIdx.x >> 5, lane = threadIdx.x & 31;
    int g = blockIdx.x * 8 + grp;

    int r, h, orow;
    size_t qoff, kbase, vbase;
    const float* bias_h; const int* offs; const int* colp;
    if (g < T_NODES * HEADS) {
        r = g >> 4; h = g & 15;
        qoff  = (size_t)r * 1536 + h*32;
        kbase = (size_t)T_NODES * 1536 + h*32;          // + c*1536
        vbase = (size_t)T_NODES * 1536 + 512 + h*32;
        bias_h = biasp_t + (size_t)h * E_T;
        offs = off_t; colp = colp_t;
        orow = C_NODES + r;
    } else {
        int g2 = g - T_NODES * HEADS;
        r = g2 >> 4; h = g2 & 15;
        qoff  = (size_t)(T_NODES + r) * 1536 + 1024 + h*32;
        kbase = 512 + h*32;
        vbase = 1024 + h*32;
        bias_h = biasp_c + (size_t)h * E_C;
        offs = off_c; colp = colp_c;
        orow = r;
    }

    float qf[32];
    {
        const short8* qp = (const short8*)(qkv + qoff);
        #pragma unroll
        for (int jj = 0; jj < 4; ++jj) {
            short8 qq = qp[jj];
            #pragma unroll
            for (int j2 = 0; j2 < 8; ++j2) qf[jj*8+j2] = bf2f((unsigned short)qq[j2]);
        }
    }

    int beg = offs[r], end = offs[r+1];
    float m = -INFINITY, l = 0.f, acc = 0.f;

    for (int i0 = beg; i0 < end; i0 += 32) {
        int i = i0 + lane;
        bool ok = i < end;
        int c = ok ? colp[i] : 0;
        float s = -INFINITY;
        if (ok) {
            float bv = bias_h[i];
            const short8* kp = (const short8*)(qkv + kbase + (size_t)c * 1536);
            float d = 0.f;
            #pragma unroll
            for (int jj = 0; jj < 4; ++jj) {
                short8 kk = kp[jj];
                #pragma unroll
                for (int j2 = 0; j2 < 8; ++j2) d += qf[jj*8+j2] * bf2f((unsigned short)kk[j2]);
            }
            s = d * SCALE_QK + bv;
        }
        float cm = s;
        #pragma unroll
        for (int o2 = 16; o2 >= 1; o2 >>= 1) cm = fmaxf(cm, __shfl_xor(cm, o2, 32));
        float m_new = fmaxf(m, cm);
        float sc = __expf(m - m_new);
        float pw = __expf(s - m_new);
        float ps = pw;
        #pragma unroll
        for (int o2 = 16; o2 >= 1; o2 >>= 1) ps += __shfl_xor(ps, o2, 32);
        l = l * sc + ps;
        acc *= sc;
        int nv = min(32, end - i0);
        for (int e2 = 0; e2 < nv; ++e2) {
            float pwb = __shfl(pw, e2, 32);
            int   cb  = __shfl(c,  e2, 32);
            acc += pwb * bf2f(qkv[vbase + (size_t)cb * 1536 + lane]);
        }
        m = m_new;
    }
    ob[(size_t)orow * H_DIM + h*32 + lane] = f2bf(acc / (l + 1e-16f));
}

// ================= launcher =================
extern "C" void kernel_launch(void* const* d_in, const int* in_sizes, int n_in,
                              void* d_out, int out_size, void* d_ws, size_t ws_size,
                              hipStream_t stream)
{
    const float* node_feats = (const float*)d_in[0];
    const float* edge_emb   = (const float*)d_in[1];
    const float* dist_emb   = (const float*)d_in[2];
    const float* w_node     = (const float*)d_in[3];
    const float* b_node     = (const float*)d_in[4];
    const float* w_enc      = (const float*)d_in[5];
    const float* b_enc      = (const float*)d_in[6];
    const float* w_dist     = (const float*)d_in[7];
    const float* b_dist     = (const float*)d_in[8];
    const float* ln1_g      = (const float*)d_in[9];
    const float* ln1_b      = (const float*)d_in[10];
    const float* attn1_w    = (const float*)d_in[11];
    const float* attn1_b    = (const float*)d_in[12];
    const float* attn2_w    = (const float*)d_in[13];
    const float* attn2_b    = (const float*)d_in[14];
    const float* ln2_g      = (const float*)d_in[15];
    const float* ln2_b      = (const float*)d_in[16];
    const float* ffn_w1     = (const float*)d_in[17];
    const float* ffn_b1     = (const float*)d_in[18];
    const float* ffn_w2     = (const float*)d_in[19];
    const float* ffn_b2     = (const float*)d_in[20];
    const int* enc          = (const int*)d_in[21];
    const int* dist         = (const int*)d_in[22];
    const int* t_row        = (const int*)d_in[23];
    const int* t_col        = (const int*)d_in[24];
    const int* c_row        = (const int*)d_in[25];
    const int* c_col        = (const int*)d_in[26];

    float* x = (float*)d_out;

    char* w = (char*)d_ws;
    auto alloc = [&](size_t bytes) { char* p = w; w += (bytes + 255) & ~(size_t)255; return p; };

    unsigned short* qkv  = (unsigned short*)alloc((size_t)N_NODES*1536*2);   // also nfb, h1
    unsigned short* nfb  = qkv;
    unsigned short* h1   = qkv;
    unsigned short* yb   = (unsigned short*)alloc((size_t)N_NODES*H_DIM*2);
    unsigned short* ob   = (unsigned short*)alloc((size_t)N_NODES*H_DIM*2);
    float* biasp_t       = (float*)alloc((size_t)HEADS*E_T*4);
    float* biasp_c       = (float*)alloc((size_t)HEADS*E_C*4);
    int* colp_t          = (int*)alloc((size_t)E_T*4);
    int* colp_c          = (int*)alloc((size_t)E_C*4);
    int* cnt_t           = (int*)alloc(T_NODES*4);       // cnt_t/cnt_c adjacent: single memset
    int* cnt_c           = (int*)alloc(C_NODES*4);
    int* off_t           = (int*)alloc((T_NODES+1)*4);
    int* cur_t           = (int*)alloc(T_NODES*4);
    int* perm_t          = (int*)alloc((size_t)E_T*4);
    int* off_c           = (int*)alloc((C_NODES+1)*4);
    int* cur_c           = (int*)alloc(C_NODES*4);
    int* perm_c          = (int*)alloc((size_t)E_C*4);
    float* P1            = (float*)alloc(256*4);
    float* P2            = (float*)alloc(128*4);
    unsigned short* wcat_t = (unsigned short*)alloc((size_t)2*1536*512*2);
    unsigned short* wcat_c = (unsigned short*)alloc((size_t)2*1536*512*2);
    unsigned short* wo1    = (unsigned short*)alloc((size_t)2*512*512*2);
    unsigned short* wo2    = (unsigned short*)alloc((size_t)2*512*512*2);
    unsigned short* wf1    = (unsigned short*)alloc((size_t)2*512*512*2);
    unsigned short* wf2    = (unsigned short*)alloc((size_t)2*512*512*2);
    unsigned short* wnT    = (unsigned short*)alloc((size_t)H_DIM*F_IN*2);
    float* bcat_t        = (float*)alloc(2*1536*4);
    float* bcat_c        = (float*)alloc(2*1536*4);

    const size_t SZ = 512*512;
    const int BIG = 1 << 30;

    // ---- fused preprocessing ----
    TD td;
    for (int l = 0; l < 2; ++l) {
        int b = l*10;
        td.src[b+0] = attn1_w + (size_t)(l*4+0)*SZ;  td.dst[b+0] = wcat_t + (size_t)l*1536*512;
        td.src[b+1] = attn2_w + (size_t)(l*4+1)*SZ;  td.dst[b+1] = wcat_t + (size_t)l*1536*512 + SZ;
        td.src[b+2] = attn2_w + (size_t)(l*4+2)*SZ;  td.dst[b+2] = wcat_t + (size_t)l*1536*512 + 2*SZ;
        td.src[b+3] = attn1_w + (size_t)(l*4+1)*SZ;  td.dst[b+3] = wcat_c + (size_t)l*1536*512;
        td.src[b+4] = attn1_w + (size_t)(l*4+2)*SZ;  td.dst[b+4] = wcat_c + (size_t)l*1536*512 + SZ;
        td.src[b+5] = attn2_w + (size_t)(l*4+0)*SZ;  td.dst[b+5] = wcat_c + (size_t)l*1536*512 + 2*SZ;
        td.src[b+6] = attn1_w + (size_t)(l*4+3)*SZ;  td.dst[b+6] = wo1 + (size_t)l*SZ;
        td.src[b+7] = attn2_w + (size_t)(l*4+3)*SZ;  td.dst[b+7] = wo2 + (size_t)l*SZ;
        td.src[b+8] = ffn_w1  + (size_t)l*SZ;        td.dst[b+8] = wf1 + (size_t)l*SZ;
        td.src[b+9] = ffn_w2  + (size_t)l*SZ;        td.dst[b+9] = wf2 + (size_t)l*SZ;
    }
    prep_kernel<<<dim3(16,16,22), 256, 0, stream>>>(td, w_node, wnT, node_feats, nfb);
    proj_kernel<<<97, 256, 0, stream>>>(edge_emb, dist_emb, w_enc, w_dist,
                                        attn1_b, attn2_b, P1, P2, bcat_t, bcat_c);

    // ---- CSR (cnt_t/cnt_c contiguous -> one memset) ----
    hipMemsetAsync(cnt_t, 0, (T_NODES + C_NODES)*4, stream);
    hist2_kernel<<<(E_T+E_C)/256, 256, 0, stream>>>(t_row, c_row, cnt_t, cnt_c);
    scan2_kernel<<<2, 1024, 0, stream>>>(cnt_t, off_t, cur_t, cnt_c, off_c, cur_c);
    scatter2_kernel<<<(E_T+E_C)/256, 256, 0, stream>>>(t_row, c_row, cur_t, cur_c, perm_t, perm_c);
    bias2_kernel<<<(E_T+E_C)/256, 256, 0, stream>>>(t_row, t_col, c_row, c_col, perm_t, perm_c,
                                                    enc, dist, P1, P2, b_enc, b_dist,
                                                    biasp_t, biasp_c, colp_t, colp_c);

    // ---- x = node_feats @ w_node + b_node ----
    gemm_bf16<0><<<dim3(8, 32), 256, 0, stream>>>(nfb, F_IN, wnT, wnT, F_IN,
                                                  b_node, b_node, x, H_DIM, F_IN, BIG);

    for (int l = 0; l < 2; ++l) {
        ln_kernel<<<N_NODES/4, 256, 0, stream>>>(x, ln1_g + l*H_DIM, ln1_b + l*H_DIM, yb, N_NODES);

        // fused QKV: rows<T use wcat_t, rows>=T use wcat_c -> qkv bf16 [4096][1536]
        gemm_bf16<3><<<dim3(24, 32), 256, 0, stream>>>(yb, H_DIM,
            wcat_t + (size_t)l*1536*512, wcat_c + (size_t)l*1536*512, H_DIM,
            bcat_t + l*1536, bcat_c + l*1536, qkv, 1536, H_DIM, T_NODES);

        // fused attention (both sides)
        attn_fused<<<(T_NODES + C_NODES)*HEADS/8, 256, 0, stream>>>(
            qkv, biasp_t, biasp_c, off_t, colp_t, off_c, colp_c, ob);

        // fused out-proj: rows<C use wo2 (attn2), rows>=C use wo1 (attn1); += into x
        gemm_bf16<2><<<dim3(8, 32), 256, 0, stream>>>(ob, H_DIM,
            wo2 + (size_t)l*SZ, wo1 + (size_t)l*SZ, H_DIM,
            attn2_b + (size_t)(l*4+3)*H_DIM, attn1_b + (size_t)(l*4+3)*H_DIM,
            x, H_DIM, H_DIM, C_NODES);

        // FFN
        ln_kernel<<<N_NODES/4, 256, 0, stream>>>(x, ln2_g + l*H_DIM, ln2_b + l*H_DIM, yb, N_NODES);
        gemm_bf16<1><<<dim3(8, 32), 256, 0, stream>>>(yb, H_DIM,
            wf1 + (size_t)l*SZ, wf1 + (size_t)l*SZ, H_DIM,
            ffn_b1 + l*H_DIM, ffn_b1 + l*H_DIM, h1, H_DIM, H_DIM, BIG);
        gemm_bf16<2><<<dim3(8, 32), 256, 0, stream>>>(h1, H_DIM,
            wf2 + (size_t)l*SZ, wf2 + (size_t)l*SZ, H_DIM,
            ffn_b2 + l*H_DIM, ffn_b2 + l*H_DIM, x, H_DIM, H_DIM, BIG);
    }
}

// Round 4
// 313.731 us; speedup vs baseline: 5.5589x; 1.1514x over previous
//
#include <hip/hip_runtime.h>
#include <math.h>

#define N_NODES 4096
#define T_NODES 1024
#define C_NODES 3072
#define F_IN    128
#define H_DIM   512
#define HEADS   16
#define D_HEAD  32
#define E_T     65536
#define E_C     98304
#define SCALE_QK 0.17677669529663687f   // 32^-0.5

typedef __attribute__((ext_vector_type(8))) short short8;
typedef __attribute__((ext_vector_type(4))) float f32x4;

struct ushort4_t { unsigned short x, y, z, w; };

__device__ inline unsigned short f2bf(float f) {
    unsigned u = __float_as_uint(f);
    unsigned r = (u + 0x7fffu + ((u >> 16) & 1u)) >> 16;
    return (unsigned short)r;
}
__device__ inline float bf2f(unsigned short u) {
    return __uint_as_float(((unsigned)u) << 16);
}

__device__ inline void gload16(const void* g, void* l) {
    __builtin_amdgcn_global_load_lds(
        (const __attribute__((address_space(1))) unsigned int*)g,
        (__attribute__((address_space(3))) unsigned int*)l, 16, 0, 0);
}

// ================= fused preprocessing: transposes + node-feat convert =================
struct TD { const float* src[20]; unsigned short* dst[20]; };

__global__ void prep_kernel(TD d, const float* __restrict__ w_node, unsigned short* __restrict__ wnT,
                            const float* __restrict__ nf, unsigned short* __restrict__ nfb)
{
    int z = blockIdx.z;
    __shared__ float tile[32][33];
    int tr = threadIdx.x >> 5, tc = threadIdx.x & 31;
    if (z < 20) {
        const float* src = d.src[z];
        unsigned short* dst = d.dst[z];
        int r0 = blockIdx.y * 32, c0 = blockIdx.x * 32;
        #pragma unroll
        for (int p = 0; p < 4; ++p) tile[tr + 8*p][tc] = src[(size_t)(r0 + tr + 8*p)*512 + c0 + tc];
        __syncthreads();
        #pragma unroll
        for (int p = 0; p < 4; ++p) dst[(size_t)(c0 + tr + 8*p)*512 + r0 + tc] = f2bf(tile[tc][tr + 8*p]);
    } else if (z == 20) {
        if (blockIdx.y >= 4) return;   // w_node is 128x512
        int r0 = blockIdx.y * 32, c0 = blockIdx.x * 32;
        #pragma unroll
        for (int p = 0; p < 4; ++p) tile[tr + 8*p][tc] = w_node[(size_t)(r0 + tr + 8*p)*512 + c0 + tc];
        __syncthreads();
        #pragma unroll
        for (int p = 0; p < 4; ++p) wnT[(size_t)(c0 + tr + 8*p)*128 + r0 + tc] = f2bf(tile[tc][tr + 8*p]);
    } else {
        int gid = (blockIdx.y * 16 + blockIdx.x) * 256 + threadIdx.x;
        #pragma unroll
        for (int rep = 0; rep < 2; ++rep) {
            int i = gid + rep * 65536;
            float4 v = ((const float4*)nf)[i];
            ushort4_t o = { f2bf(v.x), f2bf(v.y), f2bf(v.z), f2bf(v.w) };
            ((ushort4_t*)nfb)[i] = o;
        }
    }
}

// ================= P1/P2 tables (wave-per-output) + bias concat =================
__global__ void proj_kernel(const float* __restrict__ emb, const float* __restrict__ dist_emb,
                            const float* __restrict__ w_enc, const float* __restrict__ w_dist,
                            const float* __restrict__ a1b, const float* __restrict__ a2b,
                            float* __restrict__ P1, float* __restrict__ P2,
                            float* __restrict__ bct, float* __restrict__ bcc)
{
    if (blockIdx.x == 96) {
        int t = threadIdx.x;
        for (int l = 0; l < 2; ++l)
            for (int i = t; i < 512; i += 256) {
                bct[l*1536 + i]        = a1b[(l*4+0)*512 + i];
                bct[l*1536 + 512 + i]  = a2b[(l*4+1)*512 + i];
                bct[l*1536 + 1024 + i] = a2b[(l*4+2)*512 + i];
                bcc[l*1536 + i]        = a1b[(l*4+1)*512 + i];
                bcc[l*1536 + 512 + i]  = a1b[(l*4+2)*512 + i];
                bcc[l*1536 + 1024 + i] = a2b[(l*4+0)*512 + i];
            }
        return;
    }
    int wid = threadIdx.x >> 6, lane = threadIdx.x & 63;
    int o = blockIdx.x * 4 + wid;
    const float* src; const float* wm; float* dst; int h;
    if (o < 256) { src = emb      + (size_t)(o >> 4) * 512; wm = w_enc;  h = o & 15;  dst = P1 + o; }
    else { int o2 = o - 256; src = dist_emb + (size_t)(o2 >> 4) * 512; wm = w_dist; h = o2 & 15; dst = P2 + o2; }
    float4 v0 = ((const float4*)src)[lane*2];
    float4 v1 = ((const float4*)src)[lane*2+1];
    float nrm = v0.x*v0.x + v0.y*v0.y + v0.z*v0.z + v0.w*v0.w
              + v1.x*v1.x + v1.y*v1.y + v1.z*v1.z + v1.w*v1.w;
    int f0 = lane * 8;
    float dt = v0.x*wm[(f0+0)*16+h] + v0.y*wm[(f0+1)*16+h] + v0.z*wm[(f0+2)*16+h] + v0.w*wm[(f0+3)*16+h]
             + v1.x*wm[(f0+4)*16+h] + v1.y*wm[(f0+5)*16+h] + v1.z*wm[(f0+6)*16+h] + v1.w*wm[(f0+7)*16+h];
    #pragma unroll
    for (int s = 1; s < 64; s <<= 1) { nrm += __shfl_xor(nrm, s, 64); dt += __shfl_xor(dt, s, 64); }
    if (lane == 0) *dst = dt / fmaxf(sqrtf(nrm), 1.0f);
}

// ================= CSR build (both sides fused) =================
__global__ void hist2_kernel(const int* __restrict__ t_row, const int* __restrict__ c_row,
                             int* __restrict__ cnt_t, int* __restrict__ cnt_c) {
    int i = blockIdx.x * 256 + threadIdx.x;
    if (i < E_T) atomicAdd(&cnt_t[t_row[i]], 1);
    else atomicAdd(&cnt_c[c_row[i - E_T]], 1);
}

__global__ void scan2_kernel(const int* __restrict__ cnt_t, int* __restrict__ off_t, int* __restrict__ cur_t,
                             const int* __restrict__ cnt_c, int* __restrict__ off_c, int* __restrict__ cur_c) {
    const int* counts; int* offsets; int* cursor; int n;
    if (blockIdx.x == 0) { counts = cnt_t; offsets = off_t; cursor = cur_t; n = T_NODES; }
    else                 { counts = cnt_c; offsets = off_c; cursor = cur_c; n = C_NODES; }
    __shared__ int lds[1024];
    int t = threadIdx.x;
    int c = (n + 1023) / 1024;
    int base = t * c;
    int s = 0;
    for (int j = 0; j < c; ++j) { int i = base + j; if (i < n) s += counts[i]; }
    lds[t] = s;
    __syncthreads();
    for (int d = 1; d < 1024; d <<= 1) {
        int v = (t >= d) ? lds[t-d] : 0;
        __syncthreads();
        lds[t] += v;
        __syncthreads();
    }
    int run = lds[t] - s;
    for (int j = 0; j < c; ++j) {
        int i = base + j;
        if (i < n) { offsets[i] = run; cursor[i] = run; run += counts[i]; }
    }
    if (t == 1023) offsets[n] = lds[1023];
}

__global__ void scatter2_kernel(const int* __restrict__ t_row, const int* __restrict__ c_row,
                                int* __restrict__ cur_t, int* __restrict__ cur_c,
                                int* __restrict__ perm_t, int* __restrict__ perm_c) {
    int i = blockIdx.x * 256 + threadIdx.x;
    if (i < E_T) { int p = atomicAdd(&cur_t[t_row[i]], 1); perm_t[p] = i; }
    else { int j = i - E_T; int p = atomicAdd(&cur_c[c_row[j]], 1); perm_c[p] = j; }
}

// ================= per-CSR-position bias, [head][pos] planes (both sides) =================
__global__ void bias2_kernel(const int* __restrict__ t_row, const int* __restrict__ t_col,
                             const int* __restrict__ c_row, const int* __restrict__ c_col,
                             const int* __restrict__ perm_t, const int* __restrict__ perm_c,
                             const int* __restrict__ enc, const int* __restrict__ dist,
                             const float* __restrict__ P1, const float* __restrict__ P2,
                             const float* __restrict__ b_enc, const float* __restrict__ b_dist,
                             float* __restrict__ biasp_t, float* __restrict__ biasp_c,
                             int* __restrict__ colp_t, int* __restrict__ colp_c)
{
    __shared__ float sP1[256], sP2[128], sb[16];
    int t = threadIdx.x;
    sP1[t] = P1[t];
    if (t < 128) sP2[t] = P2[t];
    if (t < 16)  sb[t]  = b_enc[t] + b_dist[t];
    __syncthreads();
    int gi = blockIdx.x * 256 + t;
    if (gi < E_T) {
        int i = gi; int e = perm_t[i];
        long r = t_row[e]; long c = t_col[e];
        long idx = r * N_NODES + c + T_NODES;
        int i1 = enc[idx*2], i2 = enc[idx*2+1], j = dist[idx];
        colp_t[i] = (int)c;
        #pragma unroll
        for (int h = 0; h < 16; ++h)
            biasp_t[(size_t)h*E_T + i] = 0.5f*(sP1[i1*16+h] + sP1[i2*16+h]) + sP2[j*16+h] + sb[h];
    } else {
        int i = gi - E_T; int e = perm_c[i];
        long r = c_row[e] + T_NODES; long c = c_col[e];
        long idx = r * N_NODES + c;
        int i1 = enc[idx*2], i2 = enc[idx*2+1], j = dist[idx];
        colp_c[i] = (int)c;
        #pragma unroll
        for (int h = 0; h < 16; ++h)
            biasp_c[(size_t)h*E_C + i] = 0.5f*(sP1[i1*16+h] + sP1[i2*16+h]) + sP2[j*16+h] + sb[h];
    }
}

// ================= LayerNorm: f32 in, bf16 out (vectorized) =================
__global__ void ln_kernel(const float* __restrict__ x, const float* __restrict__ g,
                          const float* __restrict__ b, unsigned short* __restrict__ y, int M) {
    int wave = threadIdx.x >> 6;
    int lane = threadIdx.x & 63;
    int row = blockIdx.x * 4 + wave;
    if (row >= M) return;
    const float4* xr = (const float4*)(x + (size_t)row * H_DIM);
    float4 a = xr[lane*2], c4 = xr[lane*2+1];
    float s  = a.x + a.y + a.z + a.w + c4.x + c4.y + c4.z + c4.w;
    float sq = a.x*a.x + a.y*a.y + a.z*a.z + a.w*a.w + c4.x*c4.x + c4.y*c4.y + c4.z*c4.z + c4.w*c4.w;
    #pragma unroll
    for (int o = 1; o < 64; o <<= 1) { s += __shfl_xor(s, o, 64); sq += __shfl_xor(sq, o, 64); }
    float mean = s * (1.0f/512.0f);
    float var  = sq * (1.0f/512.0f) - mean*mean;
    float inv  = rsqrtf(var + 1e-5f);
    const float4* gp = (const float4*)g;
    const float4* bp = (const float4*)b;
    float4 g0 = gp[lane*2], g1 = gp[lane*2+1];
    float4 b0 = bp[lane*2], b1 = bp[lane*2+1];
    ushort4_t o0 = { f2bf((a.x-mean)*inv*g0.x + b0.x), f2bf((a.y-mean)*inv*g0.y + b0.y),
                     f2bf((a.z-mean)*inv*g0.z + b0.z), f2bf((a.w-mean)*inv*g0.w + b0.w) };
    ushort4_t o1 = { f2bf((c4.x-mean)*inv*g1.x + b1.x), f2bf((c4.y-mean)*inv*g1.y + b1.y),
                     f2bf((c4.z-mean)*inv*g1.z + b1.z), f2bf((c4.w-mean)*inv*g1.w + b1.w) };
    ushort4_t* yr = (ushort4_t*)(y + (size_t)row * H_DIM);
    yr[lane*2] = o0; yr[lane*2+1] = o1;
}

// ================= bf16 MFMA GEMM with per-block-row weight select =================
template <int MODE>
__global__ __launch_bounds__(256) void gemm_bf16(
    const unsigned short* __restrict__ A, int lda,
    const unsigned short* __restrict__ Wa, const unsigned short* __restrict__ Wb, int ldb,
    const float* __restrict__ biasa, const float* __restrict__ biasb,
    void* __restrict__ Cout, int ldc, int K, int mswitch)
{
    __shared__ unsigned short As[2][128*32];
    __shared__ unsigned short Bs[2][64*32];
    int tid  = threadIdx.x;
    int wid  = tid >> 6, lane = tid & 63;
    int wm   = wid >> 1, wn = wid & 1;
    int m0   = blockIdx.y * 128, n0 = blockIdx.x * 64;
    const unsigned short* BT = (m0 >= mswitch) ? Wb : Wa;
    const float* bias        = (m0 >= mswitch) ? biasb : biasa;

    int srow  = lane >> 2;
    int sslot = lane & 3;
    const unsigned short* Ag0 = A  + (size_t)(m0 + wid*32 + srow)*lda + sslot*8;
    const unsigned short* Ag1 = Ag0 + (size_t)16*lda;
    const unsigned short* Bg0 = BT + (size_t)(n0 + wid*16 + srow)*ldb + sslot*8;

    f32x4 acc[4][2] = {};
    int NT = K >> 5;

    auto stage = [&](int bsel, int kt) {
        char* abase = (char*)&As[bsel][0] + wid*2048;
        char* bbase = (char*)&Bs[bsel][0] + wid*1024;
        gload16(Ag0 + kt*32, abase);
        gload16(Ag1 + kt*32, abase + 1024);
        gload16(Bg0 + kt*32, bbase);
    };

    stage(0, 0);
    __syncthreads();
    int cur = 0;
    int arowf = wm*64 + (lane & 15);
    int kslot = (lane >> 4) * 8;
    for (int kt = 0; kt < NT; ++kt) {
        if (kt + 1 < NT) stage(cur ^ 1, kt + 1);
        const unsigned short* as = &As[cur][0];
        const unsigned short* bs = &Bs[cur][0];
        short8 af[4], bf[2];
        #pragma unroll
        for (int fm = 0; fm < 4; ++fm)
            af[fm] = *(const short8*)&as[(arowf + fm*16)*32 + kslot];
        #pragma unroll
        for (int fn = 0; fn < 2; ++fn)
            bf[fn] = *(const short8*)&bs[(wn*32 + fn*16 + (lane & 15))*32 + kslot];
        #pragma unroll
        for (int fm = 0; fm < 4; ++fm)
            #pragma unroll
            for (int fn = 0; fn < 2; ++fn)
                acc[fm][fn] = __builtin_amdgcn_mfma_f32_16x16x32_bf16(af[fm], bf[fn], acc[fm][fn], 0, 0, 0);
        __syncthreads();
        cur ^= 1;
    }

    int crow = m0 + wm*64 + (lane >> 4)*4;
    int ccol = n0 + wn*32 + (lane & 15);
    #pragma unroll
    for (int fn = 0; fn < 2; ++fn) {
        float bv = bias[ccol + fn*16];
        #pragma unroll
        for (int fm = 0; fm < 4; ++fm) {
            #pragma unroll
            for (int j = 0; j < 4; ++j) {
                float val = acc[fm][fn][j] + bv;
                size_t off = (size_t)(crow + fm*16 + j)*ldc + ccol + fn*16;
                if (MODE == 0) {
                    ((float*)Cout)[off] = val;
                } else if (MODE == 1) {
                    float gl = 0.5f * val * (1.0f + erff(val * 0.70710678118654752f));
                    ((unsigned short*)Cout)[off] = f2bf(gl);
                } else if (MODE == 2) {
                    ((float*)Cout)[off] += val;
                } else {
                    ((unsigned short*)Cout)[off] = f2bf(val);
                }
            }
        }
    }
}

// ================= fused segment attention (both sides, bf16 operands) =================
// qkv layout [4096][1536] bf16:
//  rows 0..T    : [q1 | k2 | v2]
//  rows T..4096 : [k1 | v1 | q2]
// ob layout [4096][512] bf16: rows 0..C = attn2 out, rows C..N = attn1 out
__global__ __launch_bounds__(256) void attn_fused(
    const unsigned short* __restrict__ qkv,
    const float* __restrict__ biasp_t, const float* __restrict__ biasp_c,
    const int* __restrict__ off_t, const int* __restrict__ colp_t,
    const int* __restrict__ off_c, const int* __restrict__ colp_c,
    unsigned short* __restrict__ ob)
{
    __shared__ float lds_pc[8][64];    // per group: 32 x (p, col-as-float-bits)
    int grp = threadIdx.x >> 5, lane = threadIdx.x & 31;
    int g = blockIdx.x * 8 + grp;

    int r, h, orow;
    size_t qoff, kbase, vbase;
    const float* bias_h; const int* offs; const int* colp;
    if (g < T_NODES * HEADS) {
        r = g >> 4; h = g & 15;
        qoff  = (size_t)r * 1536 + h*32;
        kbase = (size_t)T_NODES * 1536 + h*32;
        vbase = (size_t)T_NODES * 1536 + 512 + h*32;
        bias_h = biasp_t + (size_t)h * E_T;
        offs = off_t; colp = colp_t;
        orow = C_NODES + r;
    } else {
        int g2 = g - T_NODES * HEADS;
        r = g2 >> 4; h = g2 & 15;
        qoff  = (size_t)(T_NODES + r) * 1536 + 1024 + h*32;
        kbase = 512 + h*32;
        vbase = 1024 + h*32;
        bias_h = biasp_c + (size_t)h * E_C;
        offs = off_c; colp = colp_c;
        orow = r;
    }

    float qf[32];
    {
        const short8* qp = (const short8*)(qkv + qoff);
        #pragma unroll
        for (int jj = 0; jj < 4; ++jj) {
            short8 qq = qp[jj];
            #pragma unroll
            for (int j2 = 0; j2 < 8; ++j2) qf[jj*8+j2] = bf2f((unsigned short)qq[j2]);
        }
    }

    int beg = offs[r], end = offs[r+1];
    float m = -INFINITY, l = 0.f;
    float acc0 = 0.f, acc1 = 0.f, acc2 = 0.f, acc3 = 0.f;
    float2* pcw = (float2*)&lds_pc[grp][0];
    const float4* pcr = (const float4*)&lds_pc[grp][0];
    const unsigned short* vb = qkv + vbase;

    for (int i0 = beg; i0 < end; i0 += 32) {
        int i = i0 + lane;
        bool ok = i < end;
        int c = ok ? colp[i] : 0;
        float s = -INFINITY;
        if (ok) {
            float bv = bias_h[i];
            const short8* kp = (const short8*)(qkv + kbase + (size_t)c * 1536);
            short8 k0 = kp[0], k1 = kp[1], k2 = kp[2], k3 = kp[3];
            float d0 = 0.f, d1 = 0.f;
            #pragma unroll
            for (int j2 = 0; j2 < 8; ++j2) {
                d0 += qf[j2]      * bf2f((unsigned short)k0[j2]);
                d1 += qf[8+j2]    * bf2f((unsigned short)k1[j2]);
                d0 += qf[16+j2]   * bf2f((unsigned short)k2[j2]);
                d1 += qf[24+j2]   * bf2f((unsigned short)k3[j2]);
            }
            s = (d0 + d1) * SCALE_QK + bv;
        }
        float cm = s;
        #pragma unroll
        for (int o2 = 16; o2 >= 1; o2 >>= 1) cm = fmaxf(cm, __shfl_xor(cm, o2, 32));
        float m_new = fmaxf(m, cm);
        float sc = __expf(m - m_new);
        float pw = __expf(s - m_new);      // 0 for invalid lanes
        float ps = pw;
        #pragma unroll
        for (int o2 = 16; o2 >= 1; o2 >>= 1) ps += __shfl_xor(ps, o2, 32);
        l = l * sc + ps;
        acc0 *= sc; acc1 *= sc; acc2 *= sc; acc3 *= sc;

        // stage (p, col) into LDS; fixed-32 fully-unrolled aggregation with
        // uniform-address broadcast reads and 4 independent acc chains
        pcw[lane] = float2{ pw, __int_as_float(c) };
        #pragma unroll
        for (int j = 0; j < 32; j += 4) {
            float4 p01 = pcr[(j >> 1)];
            float4 p23 = pcr[(j >> 1) + 1];
            int c0 = __float_as_int(p01.y), c1 = __float_as_int(p01.w);
            int c2 = __float_as_int(p23.y), c3 = __float_as_int(p23.w);
            acc0 += p01.x * bf2f(vb[(size_t)c0*1536 + lane]);
            acc1 += p01.z * bf2f(vb[(size_t)c1*1536 + lane]);
            acc2 += p23.x * bf2f(vb[(size_t)c2*1536 + lane]);
            acc3 += p23.z * bf2f(vb[(size_t)c3*1536 + lane]);
        }
        m = m_new;
    }
    float acc = (acc0 + acc1) + (acc2 + acc3);
    ob[(size_t)orow * H_DIM + h*32 + lane] = f2bf(acc / (l + 1e-16f));
}

// ================= launcher =================
extern "C" void kernel_launch(void* const* d_in, const int* in_sizes, int n_in,
                              void* d_out, int out_size, void* d_ws, size_t ws_size,
                              hipStream_t stream)
{
    const float* node_feats = (const float*)d_in[0];
    const float* edge_emb   = (const float*)d_in[1];
    const float* dist_emb   = (const float*)d_in[2];
    const float* w_node     = (const float*)d_in[3];
    const float* b_node     = (const float*)d_in[4];
    const float* w_enc      = (const float*)d_in[5];
    const float* b_enc      = (const float*)d_in[6];
    const float* w_dist     = (const float*)d_in[7];
    const float* b_dist     = (const float*)d_in[8];
    const float* ln1_g      = (const float*)d_in[9];
    const float* ln1_b      = (const float*)d_in[10];
    const float* attn1_w    = (const float*)d_in[11];
    const float* attn1_b    = (const float*)d_in[12];
    const float* attn2_w    = (const float*)d_in[13];
    const float* attn2_b    = (const float*)d_in[14];
    const float* ln2_g      = (const float*)d_in[15];
    const float* ln2_b      = (const float*)d_in[16];
    const float* ffn_w1     = (const float*)d_in[17];
    const float* ffn_b1     = (const float*)d_in[18];
    const float* ffn_w2     = (const float*)d_in[19];
    const float* ffn_b2     = (const float*)d_in[20];
    const int* enc          = (const int*)d_in[21];
    const int* dist         = (const int*)d_in[22];
    const int* t_row        = (const int*)d_in[23];
    const int* t_col        = (const int*)d_in[24];
    const int* c_row        = (const int*)d_in[25];
    const int* c_col        = (const int*)d_in[26];

    float* x = (float*)d_out;

    char* w = (char*)d_ws;
    auto alloc = [&](size_t bytes) { char* p = w; w += (bytes + 255) & ~(size_t)255; return p; };

    unsigned short* qkv  = (unsigned short*)alloc((size_t)N_NODES*1536*2);   // also nfb, h1
    unsigned short* nfb  = qkv;
    unsigned short* h1   = qkv;
    unsigned short* yb   = (unsigned short*)alloc((size_t)N_NODES*H_DIM*2);
    unsigned short* ob   = (unsigned short*)alloc((size_t)N_NODES*H_DIM*2);
    float* biasp_t       = (float*)alloc((size_t)HEADS*E_T*4);
    float* biasp_c       = (float*)alloc((size_t)HEADS*E_C*4);
    int* colp_t          = (int*)alloc((size_t)E_T*4);
    int* colp_c          = (int*)alloc((size_t)E_C*4);
    int* cnt_t           = (int*)alloc(T_NODES*4);
    int* cnt_c           = (int*)alloc(C_NODES*4);
    int* off_t           = (int*)alloc((T_NODES+1)*4);
    int* cur_t           = (int*)alloc(T_NODES*4);
    int* perm_t          = (int*)alloc((size_t)E_T*4);
    int* off_c           = (int*)alloc((C_NODES+1)*4);
    int* cur_c           = (int*)alloc(C_NODES*4);
    int* perm_c          = (int*)alloc((size_t)E_C*4);
    float* P1            = (float*)alloc(256*4);
    float* P2            = (float*)alloc(128*4);
    unsigned short* wcat_t = (unsigned short*)alloc((size_t)2*1536*512*2);
    unsigned short* wcat_c = (unsigned short*)alloc((size_t)2*1536*512*2);
    unsigned short* wo1    = (unsigned short*)alloc((size_t)2*512*512*2);
    unsigned short* wo2    = (unsigned short*)alloc((size_t)2*512*512*2);
    unsigned short* wf1    = (unsigned short*)alloc((size_t)2*512*512*2);
    unsigned short* wf2    = (unsigned short*)alloc((size_t)2*512*512*2);
    unsigned short* wnT    = (unsigned short*)alloc((size_t)H_DIM*F_IN*2);
    float* bcat_t        = (float*)alloc(2*1536*4);
    float* bcat_c        = (float*)alloc(2*1536*4);

    const size_t SZ = 512*512;
    const int BIG = 1 << 30;

    // ---- fused preprocessing ----
    TD td;
    for (int l = 0; l < 2; ++l) {
        int b = l*10;
        td.src[b+0] = attn1_w + (size_t)(l*4+0)*SZ;  td.dst[b+0] = wcat_t + (size_t)l*1536*512;
        td.src[b+1] = attn2_w + (size_t)(l*4+1)*SZ;  td.dst[b+1] = wcat_t + (size_t)l*1536*512 + SZ;
        td.src[b+2] = attn2_w + (size_t)(l*4+2)*SZ;  td.dst[b+2] = wcat_t + (size_t)l*1536*512 + 2*SZ;
        td.src[b+3] = attn1_w + (size_t)(l*4+1)*SZ;  td.dst[b+3] = wcat_c + (size_t)l*1536*512;
        td.src[b+4] = attn1_w + (size_t)(l*4+2)*SZ;  td.dst[b+4] = wcat_c + (size_t)l*1536*512 + SZ;
        td.src[b+5] = attn2_w + (size_t)(l*4+0)*SZ;  td.dst[b+5] = wcat_c + (size_t)l*1536*512 + 2*SZ;
        td.src[b+6] = attn1_w + (size_t)(l*4+3)*SZ;  td.dst[b+6] = wo1 + (size_t)l*SZ;
        td.src[b+7] = attn2_w + (size_t)(l*4+3)*SZ;  td.dst[b+7] = wo2 + (size_t)l*SZ;
        td.src[b+8] = ffn_w1  + (size_t)l*SZ;        td.dst[b+8] = wf1 + (size_t)l*SZ;
        td.src[b+9] = ffn_w2  + (size_t)l*SZ;        td.dst[b+9] = wf2 + (size_t)l*SZ;
    }
    prep_kernel<<<dim3(16,16,22), 256, 0, stream>>>(td, w_node, wnT, node_feats, nfb);
    proj_kernel<<<97, 256, 0, stream>>>(edge_emb, dist_emb, w_enc, w_dist,
                                        attn1_b, attn2_b, P1, P2, bcat_t, bcat_c);

    // ---- CSR (cnt_t/cnt_c contiguous -> one memset) ----
    hipMemsetAsync(cnt_t, 0, (T_NODES + C_NODES)*4, stream);
    hist2_kernel<<<(E_T+E_C)/256, 256, 0, stream>>>(t_row, c_row, cnt_t, cnt_c);
    scan2_kernel<<<2, 1024, 0, stream>>>(cnt_t, off_t, cur_t, cnt_c, off_c, cur_c);
    scatter2_kernel<<<(E_T+E_C)/256, 256, 0, stream>>>(t_row, c_row, cur_t, cur_c, perm_t, perm_c);
    bias2_kernel<<<(E_T+E_C)/256, 256, 0, stream>>>(t_row, t_col, c_row, c_col, perm_t, perm_c,
                                                    enc, dist, P1, P2, b_enc, b_dist,
                                                    biasp_t, biasp_c, colp_t, colp_c);

    // ---- x = node_feats @ w_node + b_node ----
    gemm_bf16<0><<<dim3(8, 32), 256, 0, stream>>>(nfb, F_IN, wnT, wnT, F_IN,
                                                  b_node, b_node, x, H_DIM, F_IN, BIG);

    for (int l = 0; l < 2; ++l) {
        ln_kernel<<<N_NODES/4, 256, 0, stream>>>(x, ln1_g + l*H_DIM, ln1_b + l*H_DIM, yb, N_NODES);

        gemm_bf16<3><<<dim3(24, 32), 256, 0, stream>>>(yb, H_DIM,
            wcat_t + (size_t)l*1536*512, wcat_c + (size_t)l*1536*512, H_DIM,
            bcat_t + l*1536, bcat_c + l*1536, qkv, 1536, H_DIM, T_NODES);

        attn_fused<<<(T_NODES + C_NODES)*HEADS/8, 256, 0, stream>>>(
            qkv, biasp_t, biasp_c, off_t, colp_t, off_c, colp_c, ob);

        gemm_bf16<2><<<dim3(8, 32), 256, 0, stream>>>(ob, H_DIM,
            wo2 + (size_t)l*SZ, wo1 + (size_t)l*SZ, H_DIM,
            attn2_b + (size_t)(l*4+3)*H_DIM, attn1_b + (size_t)(l*4+3)*H_DIM,
            x, H_DIM, H_DIM, C_NODES);

        ln_kernel<<<N_NODES/4, 256, 0, stream>>>(x, ln2_g + l*H_DIM, ln2_b + l*H_DIM, yb, N_NODES);
        gemm_bf16<1><<<dim3(8, 32), 256, 0, stream>>>(yb, H_DIM,
            wf1 + (size_t)l*SZ, wf1 + (size_t)l*SZ, H_DIM,
            ffn_b1 + l*H_DIM, ffn_b1 + l*H_DIM, h1, H_DIM, H_DIM, BIG);
        gemm_bf16<2><<<dim3(8, 32), 256, 0, stream>>>(h1, H_DIM,
            wf2 + (size_t)l*SZ, wf2 + (size_t)l*SZ, H_DIM,
            ffn_b2 + l*H_DIM, ffn_b2 + l*H_DIM, x, H_DIM, H_DIM, BIG);
    }
}